// Round 4
// baseline (1078.918 us; speedup 1.0000x reference)
//
#include <hip/hip_runtime.h>
#include <hip/hip_bf16.h>
#include <math.h>

typedef __attribute__((ext_vector_type(8))) short short8;
typedef __attribute__((ext_vector_type(4))) float floatx4;

__device__ __forceinline__ float u2f(unsigned short u) {
    union { unsigned int i; float f; } x; x.i = ((unsigned int)u) << 16; return x.f;
}
__device__ __forceinline__ unsigned short f2u(float f) {
    union { float f; unsigned int i; } c; c.f = f;
    unsigned int r = c.i + 0x7FFF + ((c.i >> 16) & 1);   // round-to-nearest-even
    return (unsigned short)(r >> 16);
}
__device__ __forceinline__ float gelu_exact(float x) {
    return 0.5f * x * (1.0f + erff(x * 0.7071067811865475f));
}

// ===================== Kernel P: pack all weights to bf16, k-contiguous =====
__global__ __launch_bounds__(256) void pack_weights_k(
    const float* __restrict__ W1, const float* __restrict__ W2,
    const float* __restrict__ Wqkv, const float* __restrict__ Wp,
    const float* __restrict__ bW1, const float* __restrict__ bW2,
    const float* __restrict__ bWqkv, const float* __restrict__ bWp,
    unsigned short* __restrict__ W1t, unsigned short* __restrict__ W2t,
    unsigned short* __restrict__ Wqkvt, unsigned short* __restrict__ Wpt,
    unsigned short* __restrict__ bW1t, unsigned short* __restrict__ bW2t,
    unsigned short* __restrict__ bWqkvt, unsigned short* __restrict__ bWpt)
{
    int b = blockIdx.x, t = threadIdx.x;
    if (b < 1024) {
        W1t[(size_t)b * 256 + t] = f2u(W1[(size_t)t * 1024 + b]);
    } else if (b < 1280) {
        int n = b - 1024;
        for (int it = 0; it < 4; ++it) {
            int k = it * 256 + t;
            W2t[(size_t)n * 1024 + k] = f2u(W2[(size_t)k * 256 + n]);
        }
    } else if (b < 2048) {
        int c = b - 1280;
        Wqkvt[(size_t)c * 256 + t] = f2u(Wqkv[(size_t)t * 768 + c]);
    } else if (b < 2304) {
        int c = b - 2048;
        Wpt[(size_t)c * 256 + t] = f2u(Wp[(size_t)t * 256 + c]);
    } else if (b < 3328) {
        int c = b - 2304;
        bW1t[(size_t)c * 256 + t] = f2u(bW1[(size_t)t * 1024 + c]);
    } else if (b < 3584) {
        int n = b - 3328;
        for (int it = 0; it < 4; ++it) {
            int k = it * 256 + t;
            bW2t[(size_t)n * 1024 + k] = f2u(bW2[(size_t)k * 256 + n]);
        }
    } else if (b < 4352) {
        int c = b - 3584;
        bWqkvt[(size_t)c * 256 + t] = f2u(bWqkv[(size_t)t * 768 + c]);
    } else {
        int c = b - 4352;
        bWpt[(size_t)c * 256 + t] = f2u(bWp[(size_t)t * 256 + c]);
    }
}

// ===================== Kernel A: LN1 + window attention (MFMA) =============
// LDS union: Ybuf[64][264] (33792 B) overlaps the attention buffers (29184 B)
// -> 33.8 KB total, 4 blocks/CU. 2 barriers per head (kb/Vt are the only
// cross-wave buffers; Pb/Ob are same-wave write->read).
__global__ __launch_bounds__(256, 3) void attn_mfma_k(
    const float* __restrict__ x, const float* __restrict__ mask,
    const float* __restrict__ adj,
    const float* __restrict__ g1, const float* __restrict__ be1,
    const unsigned short* __restrict__ Wqkvt, const float* __restrict__ Bqkv,
    const unsigned short* __restrict__ Wpt, const float* __restrict__ Bp,
    float* __restrict__ out)
{
    __shared__ __align__(16) unsigned char smem[33792];
    unsigned short (*Ybuf)[264] = (unsigned short (*)[264])smem;           // dead after hoist
    unsigned short (*qb)[40]    = (unsigned short (*)[40])(smem);          //  5120
    unsigned short (*kb)[40]    = (unsigned short (*)[40])(smem + 5120);   //  5120
    unsigned short (*Vt)[72]    = (unsigned short (*)[72])(smem + 10240);  //  4608
    unsigned short (*Pb)[72]    = (unsigned short (*)[72])(smem + 14848);  //  9216
    unsigned short (*Ob)[40]    = (unsigned short (*)[40])(smem + 24064);  //  5120

    int w = blockIdx.x, p = w & 31, t = threadIdx.x;
    int wave = t >> 6, lane = t & 63;
    int l15 = lane & 15, kw = lane >> 4;
    size_t base = (size_t)w * 16384;

    // ---- LN1 -> bf16 Ybuf; out = x (residual init) ----
    for (int it = 0; it < 16; ++it) {
        int r = it * 4 + wave;
        float vals[4]; float sum = 0.f, sq = 0.f;
#pragma unroll
        for (int k2 = 0; k2 < 4; ++k2) {
            float vv = x[base + (size_t)r * 256 + lane + 64 * k2];
            vals[k2] = vv; sum += vv; sq += vv * vv;
        }
        for (int o = 32; o > 0; o >>= 1) { sum += __shfl_xor(sum, o); sq += __shfl_xor(sq, o); }
        float mu = sum * (1.f / 256.f);
        float var = sq * (1.f / 256.f) - mu * mu;
        float rstd = rsqrtf(var + 1e-5f);
#pragma unroll
        for (int k2 = 0; k2 < 4; ++k2) {
            int c = lane + 64 * k2;
            Ybuf[r][c] = f2u((vals[k2] - mu) * rstd * g1[c] + be1[c]);
            out[base + (size_t)r * 256 + c] = vals[k2];
        }
    }
    __syncthreads();

    // ---- hoist this wave's Y A-fragments into registers ----
    short8 ay[8];
#pragma unroll
    for (int ks = 0; ks < 8; ++ks)
        ay[ks] = *(const short8*)(&Ybuf[wave * 16 + l15][ks * 32 + kw * 8]);

    float ladj[4][4];
#pragma unroll
    for (int cf = 0; cf < 4; ++cf)
#pragma unroll
        for (int jj = 0; jj < 4; ++jj) {
            int r = wave * 16 + kw * 4 + jj;
            int c = cf * 16 + l15;
            ladj[cf][jj] = logf(adj[r * 64 + c] + 1e-6f);
        }

    floatx4 oacc[16];
#pragma unroll
    for (int cf = 0; cf < 16; ++cf) {
        float bb = Bp[cf * 16 + l15];
        oacc[cf] = (floatx4){bb, bb, bb, bb};
    }
    __syncthreads();   // Ybuf reads complete before qb/kb/Vt overlap-writes

    const float sc = 0.17677669529663689f;

    for (int h = 0; h < 8; ++h) {
        // ---- QKV GEMM (B-frags direct from L2-resident packed weights) ----
        floatx4 qacc[6];
#pragma unroll
        for (int cf = 0; cf < 6; ++cf) {
            int gcol = (cf >> 1) * 256 + h * 32 + (cf & 1) * 16 + l15;
            float bb = Bqkv[gcol];
            qacc[cf] = (floatx4){bb, bb, bb, bb};
        }
#pragma unroll
        for (int ks = 0; ks < 8; ++ks) {
            short8 bw[6];
#pragma unroll
            for (int cf = 0; cf < 6; ++cf) {
                int gcol = (cf >> 1) * 256 + h * 32 + (cf & 1) * 16 + l15;
                bw[cf] = *(const short8*)(Wqkvt + (size_t)gcol * 256 + ks * 32 + kw * 8);
            }
#pragma unroll
            for (int cf = 0; cf < 6; ++cf)
                qacc[cf] = __builtin_amdgcn_mfma_f32_16x16x32_bf16(ay[ks], bw[cf], qacc[cf], 0, 0, 0);
        }
#pragma unroll
        for (int cf = 0; cf < 6; ++cf)
#pragma unroll
            for (int jj = 0; jj < 4; ++jj) {
                int r = wave * 16 + kw * 4 + jj;
                int d = (cf & 1) * 16 + l15;
                unsigned short ub = f2u(qacc[cf][jj]);
                if (cf < 2) qb[r][d] = ub;
                else if (cf < 4) kb[r][d] = ub;
                else Vt[d][r] = ub;
            }
        __syncthreads();   // kb/Vt ready for cross-wave reads

        // ---- scores S = Q K^T + in-register softmax ----
        short8 aq = *(const short8*)(&qb[wave * 16 + l15][kw * 8]);
        floatx4 sacc[4];
#pragma unroll
        for (int cf = 0; cf < 4; ++cf) {
            short8 bk = *(const short8*)(&kb[cf * 16 + l15][kw * 8]);
            sacc[cf] = __builtin_amdgcn_mfma_f32_16x16x32_bf16(aq, bk,
                        (floatx4){0.f, 0.f, 0.f, 0.f}, 0, 0, 0);
        }
#pragma unroll
        for (int jj = 0; jj < 4; ++jj) {
            float s0 = sacc[0][jj] * sc + ladj[0][jj];
            float s1 = sacc[1][jj] * sc + ladj[1][jj];
            float s2 = sacc[2][jj] * sc + ladj[2][jj];
            float s3 = sacc[3][jj] * sc + ladj[3][jj];
            float mx = fmaxf(fmaxf(s0, s1), fmaxf(s2, s3));
            mx = fmaxf(mx, __shfl_xor(mx, 1));
            mx = fmaxf(mx, __shfl_xor(mx, 2));
            mx = fmaxf(mx, __shfl_xor(mx, 4));
            mx = fmaxf(mx, __shfl_xor(mx, 8));
            float e0 = __expf(s0 - mx), e1 = __expf(s1 - mx);
            float e2 = __expf(s2 - mx), e3 = __expf(s3 - mx);
            float sum = e0 + e1 + e2 + e3;
            sum += __shfl_xor(sum, 1);
            sum += __shfl_xor(sum, 2);
            sum += __shfl_xor(sum, 4);
            sum += __shfl_xor(sum, 8);
            float inv = 1.f / sum;
            int r = wave * 16 + kw * 4 + jj;
            Pb[r][0 * 16 + l15] = f2u(e0 * inv);
            Pb[r][1 * 16 + l15] = f2u(e1 * inv);
            Pb[r][2 * 16 + l15] = f2u(e2 * inv);
            Pb[r][3 * 16 + l15] = f2u(e3 * inv);
        }
        // Pb is same-wave write->read: no barrier needed.

        // ---- PV: O = P @ V ----
        floatx4 oacc2[2];
#pragma unroll
        for (int cf2 = 0; cf2 < 2; ++cf2) oacc2[cf2] = (floatx4){0.f, 0.f, 0.f, 0.f};
#pragma unroll
        for (int ks = 0; ks < 2; ++ks) {
            short8 ap = *(const short8*)(&Pb[wave * 16 + l15][ks * 32 + kw * 8]);
#pragma unroll
            for (int cf2 = 0; cf2 < 2; ++cf2) {
                short8 bv = *(const short8*)(&Vt[cf2 * 16 + l15][ks * 32 + kw * 8]);
                oacc2[cf2] = __builtin_amdgcn_mfma_f32_16x16x32_bf16(ap, bv, oacc2[cf2], 0, 0, 0);
            }
        }
#pragma unroll
        for (int cf2 = 0; cf2 < 2; ++cf2)
#pragma unroll
            for (int jj = 0; jj < 4; ++jj)
                Ob[wave * 16 + kw * 4 + jj][cf2 * 16 + l15] = f2u(oacc2[cf2][jj]);
        __syncthreads();   // all cross-wave kb/Vt reads done before next head's writes

        // ---- proj accumulate (Ob same-wave; Wpt from L2) ----
        short8 ao = *(const short8*)(&Ob[wave * 16 + l15][kw * 8]);
#pragma unroll
        for (int cf = 0; cf < 16; ++cf) {
            short8 bw = *(const short8*)(Wpt + (size_t)(cf * 16 + l15) * 256 + h * 32 + kw * 8);
            oacc[cf] = __builtin_amdgcn_mfma_f32_16x16x32_bf16(ao, bw, oacc[cf], 0, 0, 0);
        }
    }

    // ---- epilogue: out += oacc * mask[p][row] ----
#pragma unroll
    for (int jj = 0; jj < 4; ++jj) {
        int r = wave * 16 + kw * 4 + jj;
        float mv = mask[p * 64 + r];
#pragma unroll
        for (int cf = 0; cf < 16; ++cf) {
            size_t idx = base + (size_t)r * 256 + cf * 16 + l15;
            out[idx] += oacc[cf][jj] * mv;
        }
    }
}

// ===================== Kernel B: LN2 + MLP residual (MFMA) + pooled zsum ===
// B-frags direct from global (no Wbuf staging): 2 barriers per pass.
// Epilogue fuses the masked column-sum -> zsum[w][c].
__global__ __launch_bounds__(256, 3) void mlp_mfma_k(
    const float* __restrict__ mask,
    const float* __restrict__ g2, const float* __restrict__ be2,
    const unsigned short* __restrict__ W1t, const float* __restrict__ B1,
    const unsigned short* __restrict__ W2t, const float* __restrict__ B2,
    float* __restrict__ out, float* __restrict__ zsum)
{
    __shared__ __align__(16) unsigned char smem[33792];
    unsigned short (*Ybuf)[264] = (unsigned short (*)[264])smem;   // dead after hoist
    unsigned short (*Hbuf)[72]  = (unsigned short (*)[72])smem;    // 9216 B

    int w = blockIdx.x, p = w & 31, t = threadIdx.x;
    int wave = t >> 6, lane = t & 63;
    int l15 = lane & 15, kw = lane >> 4;
    size_t base = (size_t)w * 16384;

    for (int it = 0; it < 16; ++it) {
        int r = it * 4 + wave;
        float vals[4]; float sum = 0.f, sq = 0.f;
#pragma unroll
        for (int k2 = 0; k2 < 4; ++k2) {
            float vv = out[base + (size_t)r * 256 + lane + 64 * k2];
            vals[k2] = vv; sum += vv; sq += vv * vv;
        }
        for (int o = 32; o > 0; o >>= 1) { sum += __shfl_xor(sum, o); sq += __shfl_xor(sq, o); }
        float mu = sum * (1.f / 256.f);
        float var = sq * (1.f / 256.f) - mu * mu;
        float rstd = rsqrtf(var + 1e-5f);
#pragma unroll
        for (int k2 = 0; k2 < 4; ++k2) {
            int c = lane + 64 * k2;
            Ybuf[r][c] = f2u((vals[k2] - mu) * rstd * g2[c] + be2[c]);
        }
    }
    __syncthreads();

    short8 ay[8];
#pragma unroll
    for (int ks = 0; ks < 8; ++ks)
        ay[ks] = *(const short8*)(&Ybuf[wave * 16 + l15][ks * 32 + kw * 8]);
    __syncthreads();   // Ybuf reads complete before Hbuf overlap-writes

    floatx4 oacc[4][4];
#pragma unroll
    for (int m = 0; m < 4; ++m)
#pragma unroll
        for (int j = 0; j < 4; ++j) {
            float bb = B2[wave * 64 + j * 16 + l15];
            oacc[m][j] = (floatx4){bb, bb, bb, bb};
        }

    for (int pass = 0; pass < 16; ++pass) {
        // ---- fc1: 64 cols, B-frags direct from W1t (L2) ----
        floatx4 facc[4];
#pragma unroll
        for (int j = 0; j < 4; ++j) {
            float bb = B1[pass * 64 + j * 16 + l15];
            facc[j] = (floatx4){bb, bb, bb, bb};
        }
#pragma unroll
        for (int ks = 0; ks < 8; ++ks) {
            short8 bf[4];
#pragma unroll
            for (int j = 0; j < 4; ++j)
                bf[j] = *(const short8*)(W1t + (size_t)(pass * 64 + j * 16 + l15) * 256 + ks * 32 + kw * 8);
#pragma unroll
            for (int j = 0; j < 4; ++j)
                facc[j] = __builtin_amdgcn_mfma_f32_16x16x32_bf16(ay[ks], bf[j], facc[j], 0, 0, 0);
        }
#pragma unroll
        for (int j = 0; j < 4; ++j)
#pragma unroll
            for (int jj = 0; jj < 4; ++jj)
                Hbuf[wave * 16 + kw * 4 + jj][j * 16 + l15] = f2u(gelu_exact(facc[j][jj]));
        __syncthreads();   // Hbuf ready for cross-wave reads

        // ---- fc2 partial (K=64), B-frags direct from W2t (L2) ----
#pragma unroll
        for (int ks2 = 0; ks2 < 2; ++ks2) {
            short8 af[4], bf[4];
#pragma unroll
            for (int m = 0; m < 4; ++m)
                af[m] = *(const short8*)(&Hbuf[m * 16 + l15][ks2 * 32 + kw * 8]);
#pragma unroll
            for (int j = 0; j < 4; ++j)
                bf[j] = *(const short8*)(W2t + (size_t)(wave * 64 + j * 16 + l15) * 1024 + pass * 64 + ks2 * 32 + kw * 8);
#pragma unroll
            for (int m = 0; m < 4; ++m)
#pragma unroll
                for (int j = 0; j < 4; ++j)
                    oacc[m][j] = __builtin_amdgcn_mfma_f32_16x16x32_bf16(af[m], bf[j], oacc[m][j], 0, 0, 0);
        }
        __syncthreads();   // Hbuf reads done before next pass overwrites
    }

    // ---- epilogue: out += oacc * mask; fused masked column-sum -> zsum ----
    float zp[4] = {0.f, 0.f, 0.f, 0.f};
#pragma unroll
    for (int m = 0; m < 4; ++m) {
#pragma unroll
        for (int jj = 0; jj < 4; ++jj) {
            int r = m * 16 + kw * 4 + jj;
            float mv = mask[p * 64 + r];
#pragma unroll
            for (int j = 0; j < 4; ++j) {
                size_t idx = base + (size_t)r * 256 + wave * 64 + j * 16 + l15;
                float nv = out[idx] + oacc[m][j][jj] * mv;
                out[idx] = nv;
                zp[j] += mv * nv;
            }
        }
    }
#pragma unroll
    for (int j = 0; j < 4; ++j) {
        zp[j] += __shfl_xor(zp[j], 16);
        zp[j] += __shfl_xor(zp[j], 32);
    }
    if (kw == 0) {
#pragma unroll
        for (int j = 0; j < 4; ++j)
            zsum[(size_t)w * 256 + wave * 64 + j * 16 + l15] = zp[j];
    }
}

// ===================== Kernel Z2: pool-finish + LN + z attn + MLP (MFMA) ====
__global__ __launch_bounds__(256) void zcompute_k(
    const float* __restrict__ zsum, const float* __restrict__ mask,
    const float* __restrict__ gvec, const float* __restrict__ bvec,
    const unsigned short* __restrict__ bWqkvt, const float* __restrict__ Bqkv,
    const unsigned short* __restrict__ bWpt, const float* __restrict__ Bp,
    const unsigned short* __restrict__ bW1t, const float* __restrict__ B1,
    const unsigned short* __restrict__ bW2t, const float* __restrict__ B2,
    float* __restrict__ zout)
{
    __shared__ unsigned short Zbuf[32][264];
    __shared__ unsigned short Z2[32][264];
    __shared__ unsigned short qb[32][40], kb[32][40], Vt[32][40], Pb[32][40], Ob[32][40];
    __shared__ unsigned short Hbuf[32][72];
    __shared__ float msh[32];
    int bt = blockIdx.x, t = threadIdx.x;
    int wave = t >> 6, lane = t & 63;
    int l15 = lane & 15, kw = lane >> 4;
    int rt = wave & 1, cq = wave >> 1;

    if (t < 32) {
        float s = 0.f;
        for (int nn = 0; nn < 64; ++nn) s += mask[t * 64 + nn];
        msh[t] = fmaxf(s, 1.f);
    }
    __syncthreads();

    // ---- pool divisor + LN over D=256, rows 32 -> bf16 Zbuf ----
    for (int it = 0; it < 8; ++it) {
        int r = it * 4 + wave;
        float inv_m = 1.f / msh[r];
        float vals[4]; float sum = 0.f, sq = 0.f;
#pragma unroll
        for (int k2 = 0; k2 < 4; ++k2) {
            float vv = zsum[(size_t)bt * 8192 + (size_t)r * 256 + lane + 64 * k2] * inv_m;
            vals[k2] = vv; sum += vv; sq += vv * vv;
        }
        for (int o = 32; o > 0; o >>= 1) { sum += __shfl_xor(sum, o); sq += __shfl_xor(sq, o); }
        float mu = sum * (1.f / 256.f);
        float var = sq * (1.f / 256.f) - mu * mu;
        float rstd = rsqrtf(var + 1e-5f);
#pragma unroll
        for (int k2 = 0; k2 < 4; ++k2) {
            int c = lane + 64 * k2;
            Zbuf[r][c] = f2u((vals[k2] - mu) * rstd * gvec[c] + bvec[c]);
        }
    }
    __syncthreads();

    short8 ay[8];
#pragma unroll
    for (int ks = 0; ks < 8; ++ks)
        ay[ks] = *(const short8*)(&Zbuf[rt * 16 + l15][ks * 32 + kw * 8]);

    floatx4 pacc[8];
#pragma unroll
    for (int cf = 0; cf < 8; ++cf) {
        float bb = Bp[cq * 128 + cf * 16 + l15];
        pacc[cf] = (floatx4){bb, bb, bb, bb};
    }
    const float sc = 0.17677669529663689f;

    for (int h = 0; h < 8; ++h) {
        floatx4 qacc[3];
#pragma unroll
        for (int cf = 0; cf < 3; ++cf) {
            int c96 = cq * 48 + cf * 16 + l15;
            int gcol = (c96 >> 5) * 256 + h * 32 + (c96 & 31);
            float bb = Bqkv[gcol];
            qacc[cf] = (floatx4){bb, bb, bb, bb};
        }
#pragma unroll
        for (int ks = 0; ks < 8; ++ks) {
#pragma unroll
            for (int cf = 0; cf < 3; ++cf) {
                int c96 = cq * 48 + cf * 16 + l15;
                int gcol = (c96 >> 5) * 256 + h * 32 + (c96 & 31);
                short8 bw = *(const short8*)(bWqkvt + (size_t)gcol * 256 + ks * 32 + kw * 8);
                qacc[cf] = __builtin_amdgcn_mfma_f32_16x16x32_bf16(ay[ks], bw, qacc[cf], 0, 0, 0);
            }
        }
#pragma unroll
        for (int cf = 0; cf < 3; ++cf) {
            int c96 = cq * 48 + cf * 16 + l15;
            int which = c96 >> 5, d = c96 & 31;
#pragma unroll
            for (int jj = 0; jj < 4; ++jj) {
                int r = rt * 16 + kw * 4 + jj;
                unsigned short ub = f2u(qacc[cf][jj]);
                if (which == 0) qb[r][d] = ub;
                else if (which == 1) kb[r][d] = ub;
                else Vt[d][r] = ub;
            }
        }
        __syncthreads();
        if (wave < 2) {
            short8 aq = *(const short8*)(&qb[wave * 16 + l15][kw * 8]);
            floatx4 sacc[2];
#pragma unroll
            for (int cf = 0; cf < 2; ++cf) {
                short8 bk = *(const short8*)(&kb[cf * 16 + l15][kw * 8]);
                sacc[cf] = __builtin_amdgcn_mfma_f32_16x16x32_bf16(aq, bk,
                            (floatx4){0.f, 0.f, 0.f, 0.f}, 0, 0, 0);
            }
#pragma unroll
            for (int jj = 0; jj < 4; ++jj) {
                float s0 = sacc[0][jj] * sc;
                float s1 = sacc[1][jj] * sc;
                float mx = fmaxf(s0, s1);
                mx = fmaxf(mx, __shfl_xor(mx, 1));
                mx = fmaxf(mx, __shfl_xor(mx, 2));
                mx = fmaxf(mx, __shfl_xor(mx, 4));
                mx = fmaxf(mx, __shfl_xor(mx, 8));
                float e0 = __expf(s0 - mx), e1 = __expf(s1 - mx);
                float sum = e0 + e1;
                sum += __shfl_xor(sum, 1);
                sum += __shfl_xor(sum, 2);
                sum += __shfl_xor(sum, 4);
                sum += __shfl_xor(sum, 8);
                float inv = 1.f / sum;
                int r = wave * 16 + kw * 4 + jj;
                Pb[r][l15] = f2u(e0 * inv);
                Pb[r][16 + l15] = f2u(e1 * inv);
            }
        }
        __syncthreads();
        {
            short8 ap = *(const short8*)(&Pb[rt * 16 + l15][kw * 8]);
            short8 bv = *(const short8*)(&Vt[cq * 16 + l15][kw * 8]);
            floatx4 oo = __builtin_amdgcn_mfma_f32_16x16x32_bf16(ap, bv,
                          (floatx4){0.f, 0.f, 0.f, 0.f}, 0, 0, 0);
#pragma unroll
            for (int jj = 0; jj < 4; ++jj)
                Ob[rt * 16 + kw * 4 + jj][cq * 16 + l15] = f2u(oo[jj]);
        }
        __syncthreads();
        {
            short8 ao = *(const short8*)(&Ob[rt * 16 + l15][kw * 8]);
#pragma unroll
            for (int cf = 0; cf < 8; ++cf) {
                int gcol = cq * 128 + cf * 16 + l15;
                short8 bw = *(const short8*)(bWpt + (size_t)gcol * 256 + h * 32 + kw * 8);
                pacc[cf] = __builtin_amdgcn_mfma_f32_16x16x32_bf16(ao, bw, pacc[cf], 0, 0, 0);
            }
        }
        __syncthreads();
    }
#pragma unroll
    for (int cf = 0; cf < 8; ++cf)
#pragma unroll
        for (int jj = 0; jj < 4; ++jj)
            Z2[rt * 16 + kw * 4 + jj][cq * 128 + cf * 16 + l15] = f2u(pacc[cf][jj]);
    __syncthreads();

    short8 az[8];
#pragma unroll
    for (int ks = 0; ks < 8; ++ks)
        az[ks] = *(const short8*)(&Z2[rt * 16 + l15][ks * 32 + kw * 8]);

    floatx4 oacc2[8];
#pragma unroll
    for (int cf = 0; cf < 8; ++cf) {
        float bb = B2[cq * 128 + cf * 16 + l15];
        oacc2[cf] = (floatx4){bb, bb, bb, bb};
    }
    for (int pass = 0; pass < 16; ++pass) {
        floatx4 facc[2];
#pragma unroll
        for (int cf = 0; cf < 2; ++cf) {
            int col = pass * 64 + cq * 32 + cf * 16 + l15;
            float bb = B1[col];
            facc[cf] = (floatx4){bb, bb, bb, bb};
        }
#pragma unroll
        for (int ks = 0; ks < 8; ++ks) {
#pragma unroll
            for (int cf = 0; cf < 2; ++cf) {
                int col = pass * 64 + cq * 32 + cf * 16 + l15;
                short8 bw = *(const short8*)(bW1t + (size_t)col * 256 + ks * 32 + kw * 8);
                facc[cf] = __builtin_amdgcn_mfma_f32_16x16x32_bf16(az[ks], bw, facc[cf], 0, 0, 0);
            }
        }
#pragma unroll
        for (int cf = 0; cf < 2; ++cf)
#pragma unroll
            for (int jj = 0; jj < 4; ++jj)
                Hbuf[rt * 16 + kw * 4 + jj][cq * 32 + cf * 16 + l15] = f2u(gelu_exact(facc[cf][jj]));
        __syncthreads();
#pragma unroll
        for (int ks = 0; ks < 2; ++ks) {
            short8 ah = *(const short8*)(&Hbuf[rt * 16 + l15][ks * 32 + kw * 8]);
#pragma unroll
            for (int cf = 0; cf < 8; ++cf) {
                int gcol = cq * 128 + cf * 16 + l15;
                short8 bw = *(const short8*)(bW2t + (size_t)gcol * 1024 + pass * 64 + ks * 32 + kw * 8);
                oacc2[cf] = __builtin_amdgcn_mfma_f32_16x16x32_bf16(ah, bw, oacc2[cf], 0, 0, 0);
            }
        }
        __syncthreads();
    }
#pragma unroll
    for (int cf = 0; cf < 8; ++cf)
#pragma unroll
        for (int jj = 0; jj < 4; ++jj) {
            int r = rt * 16 + kw * 4 + jj;
            int c = cq * 128 + cf * 16 + l15;
            zout[(size_t)bt * 8192 + r * 256 + c] = oacc2[cf][jj];
        }
}

// ===================== Kernel Z3: broadcast add over N ======================
__global__ __launch_bounds__(256) void zadd_k(
    const float* __restrict__ zout, float* __restrict__ out)
{
    int w = blockIdx.x, t = threadIdx.x;
    size_t base = (size_t)w * 16384;
    float zv = zout[(size_t)w * 256 + t];
    for (int nn = 0; nn < 64; ++nn)
        out[base + (size_t)nn * 256 + t] += zv;
}

extern "C" void kernel_launch(void* const* d_in, const int* in_sizes, int n_in,
                              void* d_out, int out_size, void* d_ws, size_t ws_size,
                              hipStream_t stream) {
    (void)in_sizes; (void)n_in; (void)out_size; (void)ws_size;
    const float* x        = (const float*)d_in[0];
    const float* mask     = (const float*)d_in[1];
    const float* adj      = (const float*)d_in[2];
    const float* dn1_g    = (const float*)d_in[3];
    const float* dn1_b    = (const float*)d_in[4];
    const float* dn2_g    = (const float*)d_in[5];
    const float* dn2_b    = (const float*)d_in[6];
    const float* bn1_g    = (const float*)d_in[7];
    const float* bn1_b    = (const float*)d_in[8];
    const float* d_qkv_w  = (const float*)d_in[9];
    const float* d_qkv_b  = (const float*)d_in[10];
    const float* d_proj_w = (const float*)d_in[11];
    const float* d_proj_b = (const float*)d_in[12];
    const float* d_fc1_w  = (const float*)d_in[13];
    const float* d_fc1_b  = (const float*)d_in[14];
    const float* d_fc2_w  = (const float*)d_in[15];
    const float* d_fc2_b  = (const float*)d_in[16];
    const float* b_qkv_w  = (const float*)d_in[17];
    const float* b_qkv_b  = (const float*)d_in[18];
    const float* b_proj_w = (const float*)d_in[19];
    const float* b_proj_b = (const float*)d_in[20];
    const float* b_fc1_w  = (const float*)d_in[21];
    const float* b_fc1_b  = (const float*)d_in[22];
    const float* b_fc2_w  = (const float*)d_in[23];
    const float* b_fc2_b  = (const float*)d_in[24];
    float* out = (float*)d_out;

    // workspace (shorts unless noted):
    // W1t 262144 | W2t 262144 | Wqkvt 196608 | Wpt 65536
    // bW1t 262144 | bW2t 262144 | bWqkvt 196608 | bWpt 65536
    // zsum fp32 262144 | zout fp32 262144   (~5.1 MB)
    unsigned short* W1t    = (unsigned short*)d_ws;
    unsigned short* W2t    = W1t + 262144;
    unsigned short* Wqkvt  = W2t + 262144;
    unsigned short* Wpt    = Wqkvt + 196608;
    unsigned short* bW1t   = Wpt + 65536;
    unsigned short* bW2t   = bW1t + 262144;
    unsigned short* bWqkvt = bW2t + 262144;
    unsigned short* bWpt   = bWqkvt + 196608;
    float* zsum            = (float*)(bWpt + 65536);
    float* zout            = zsum + 262144;

    pack_weights_k<<<4608, 256, 0, stream>>>(d_fc1_w, d_fc2_w, d_qkv_w, d_proj_w,
                                             b_fc1_w, b_fc2_w, b_qkv_w, b_proj_w,
                                             W1t, W2t, Wqkvt, Wpt,
                                             bW1t, bW2t, bWqkvt, bWpt);
    attn_mfma_k<<<1024, 256, 0, stream>>>(x, mask, adj, dn1_g, dn1_b,
                                          Wqkvt, d_qkv_b, Wpt, d_proj_b, out);
    mlp_mfma_k<<<1024, 256, 0, stream>>>(mask, dn2_g, dn2_b,
                                         W1t, d_fc1_b, W2t, d_fc2_b, out, zsum);
    zcompute_k<<<32, 256, 0, stream>>>(zsum, mask, bn1_g, bn1_b,
                                       bWqkvt, b_qkv_b, bWpt, b_proj_b,
                                       bW1t, b_fc1_b, bW2t, b_fc2_b, zout);
    zadd_k<<<1024, 256, 0, stream>>>(zout, out);
}

// Round 6
// 901.933 us; speedup vs baseline: 1.1962x; 1.1962x over previous
//
#include <hip/hip_runtime.h>
#include <hip/hip_bf16.h>
#include <math.h>

typedef __attribute__((ext_vector_type(8))) short short8;
typedef __attribute__((ext_vector_type(4))) float floatx4;

__device__ __forceinline__ unsigned short f2u(float f) {
    union { float f; unsigned int i; } c; c.f = f;
    unsigned int r = c.i + 0x7FFF + ((c.i >> 16) & 1);   // round-to-nearest-even
    return (unsigned short)(r >> 16);
}
__device__ __forceinline__ float gelu_exact(float x) {
    return 0.5f * x * (1.0f + erff(x * 0.7071067811865475f));
}

// ===================== Kernel P: pack all weights to bf16, k-contiguous =====
__global__ __launch_bounds__(256) void pack_weights_k(
    const float* __restrict__ W1, const float* __restrict__ W2,
    const float* __restrict__ Wqkv, const float* __restrict__ Wp,
    const float* __restrict__ bW1, const float* __restrict__ bW2,
    const float* __restrict__ bWqkv, const float* __restrict__ bWp,
    unsigned short* __restrict__ W1t, unsigned short* __restrict__ W2t,
    unsigned short* __restrict__ Wqkvt, unsigned short* __restrict__ Wpt,
    unsigned short* __restrict__ bW1t, unsigned short* __restrict__ bW2t,
    unsigned short* __restrict__ bWqkvt, unsigned short* __restrict__ bWpt)
{
    int b = blockIdx.x, t = threadIdx.x;
    if (b < 1024) {
        W1t[(size_t)b * 256 + t] = f2u(W1[(size_t)t * 1024 + b]);
    } else if (b < 1280) {
        int n = b - 1024;
        for (int it = 0; it < 4; ++it) {
            int k = it * 256 + t;
            W2t[(size_t)n * 1024 + k] = f2u(W2[(size_t)k * 256 + n]);
        }
    } else if (b < 2048) {
        int c = b - 1280;
        Wqkvt[(size_t)c * 256 + t] = f2u(Wqkv[(size_t)t * 768 + c]);
    } else if (b < 2304) {
        int c = b - 2048;
        Wpt[(size_t)c * 256 + t] = f2u(Wp[(size_t)t * 256 + c]);
    } else if (b < 3328) {
        int c = b - 2304;
        bW1t[(size_t)c * 256 + t] = f2u(bW1[(size_t)t * 1024 + c]);
    } else if (b < 3584) {
        int n = b - 3328;
        for (int it = 0; it < 4; ++it) {
            int k = it * 256 + t;
            bW2t[(size_t)n * 1024 + k] = f2u(bW2[(size_t)k * 256 + n]);
        }
    } else if (b < 4352) {
        int c = b - 3584;
        bWqkvt[(size_t)c * 256 + t] = f2u(bWqkv[(size_t)t * 768 + c]);
    } else {
        int c = b - 4352;
        bWpt[(size_t)c * 256 + t] = f2u(bWp[(size_t)t * 256 + c]);
    }
}

// ===================== Kernel A: LN1 + window attention (MFMA) =============
// LDS union: Ybuf[64][264] (33792 B) overlaps attention buffers (29184 B).
// No launch_bounds min-wave cap (R4 lesson: forced VGPR cap -> spills).
// 2 barriers per head (kb/Vt are the only cross-wave buffers).
__global__ __launch_bounds__(256) void attn_mfma_k(
    const float* __restrict__ x, const float* __restrict__ mask,
    const float* __restrict__ adj,
    const float* __restrict__ g1, const float* __restrict__ be1,
    const unsigned short* __restrict__ Wqkvt, const float* __restrict__ Bqkv,
    const unsigned short* __restrict__ Wpt, const float* __restrict__ Bp,
    float* __restrict__ out)
{
    __shared__ __align__(16) unsigned char smem[33792];
    unsigned short (*Ybuf)[264] = (unsigned short (*)[264])smem;           // dead after hoist
    unsigned short (*qb)[40]    = (unsigned short (*)[40])(smem);          //  5120
    unsigned short (*kb)[40]    = (unsigned short (*)[40])(smem + 5120);   //  5120
    unsigned short (*Vt)[72]    = (unsigned short (*)[72])(smem + 10240);  //  4608
    unsigned short (*Pb)[72]    = (unsigned short (*)[72])(smem + 14848);  //  9216
    unsigned short (*Ob)[40]    = (unsigned short (*)[40])(smem + 24064);  //  5120

    int w = blockIdx.x, p = w & 31, t = threadIdx.x;
    int wave = t >> 6, lane = t & 63;
    int l15 = lane & 15, kw = lane >> 4;
    size_t base = (size_t)w * 16384;

    // ---- LN1 -> bf16 Ybuf; out = x (residual init) ----
    for (int it = 0; it < 16; ++it) {
        int r = it * 4 + wave;
        float vals[4]; float sum = 0.f, sq = 0.f;
#pragma unroll
        for (int k2 = 0; k2 < 4; ++k2) {
            float vv = x[base + (size_t)r * 256 + lane + 64 * k2];
            vals[k2] = vv; sum += vv; sq += vv * vv;
        }
        for (int o = 32; o > 0; o >>= 1) { sum += __shfl_xor(sum, o); sq += __shfl_xor(sq, o); }
        float mu = sum * (1.f / 256.f);
        float var = sq * (1.f / 256.f) - mu * mu;
        float rstd = rsqrtf(var + 1e-5f);
#pragma unroll
        for (int k2 = 0; k2 < 4; ++k2) {
            int c = lane + 64 * k2;
            Ybuf[r][c] = f2u((vals[k2] - mu) * rstd * g1[c] + be1[c]);
            out[base + (size_t)r * 256 + c] = vals[k2];
        }
    }
    __syncthreads();

    // ---- hoist this wave's Y A-fragments into registers ----
    short8 ay[8];
#pragma unroll
    for (int ks = 0; ks < 8; ++ks)
        ay[ks] = *(const short8*)(&Ybuf[wave * 16 + l15][ks * 32 + kw * 8]);

    float ladj[4][4];
#pragma unroll
    for (int cf = 0; cf < 4; ++cf)
#pragma unroll
        for (int jj = 0; jj < 4; ++jj) {
            int r = wave * 16 + kw * 4 + jj;
            int c = cf * 16 + l15;
            ladj[cf][jj] = logf(adj[r * 64 + c] + 1e-6f);
        }

    floatx4 oacc[16];
#pragma unroll
    for (int cf = 0; cf < 16; ++cf) {
        float bb = Bp[cf * 16 + l15];
        oacc[cf] = (floatx4){bb, bb, bb, bb};
    }
    __syncthreads();   // Ybuf reads complete before qb/kb/Vt overlap-writes

    const float sc = 0.17677669529663689f;

    for (int h = 0; h < 8; ++h) {
        // ---- QKV GEMM (B-frags direct from L2-resident packed weights) ----
        floatx4 qacc[6];
#pragma unroll
        for (int cf = 0; cf < 6; ++cf) {
            int gcol = (cf >> 1) * 256 + h * 32 + (cf & 1) * 16 + l15;
            float bb = Bqkv[gcol];
            qacc[cf] = (floatx4){bb, bb, bb, bb};
        }
#pragma unroll
        for (int ks = 0; ks < 8; ++ks) {
            short8 bw[6];
#pragma unroll
            for (int cf = 0; cf < 6; ++cf) {
                int gcol = (cf >> 1) * 256 + h * 32 + (cf & 1) * 16 + l15;
                bw[cf] = *(const short8*)(Wqkvt + (size_t)gcol * 256 + ks * 32 + kw * 8);
            }
#pragma unroll
            for (int cf = 0; cf < 6; ++cf)
                qacc[cf] = __builtin_amdgcn_mfma_f32_16x16x32_bf16(ay[ks], bw[cf], qacc[cf], 0, 0, 0);
        }
#pragma unroll
        for (int cf = 0; cf < 6; ++cf)
#pragma unroll
            for (int jj = 0; jj < 4; ++jj) {
                int r = wave * 16 + kw * 4 + jj;
                int d = (cf & 1) * 16 + l15;
                unsigned short ub = f2u(qacc[cf][jj]);
                if (cf < 2) qb[r][d] = ub;
                else if (cf < 4) kb[r][d] = ub;
                else Vt[d][r] = ub;
            }
        __syncthreads();   // kb/Vt ready for cross-wave reads

        // ---- scores S = Q K^T + in-register softmax ----
        short8 aq = *(const short8*)(&qb[wave * 16 + l15][kw * 8]);
        floatx4 sacc[4];
#pragma unroll
        for (int cf = 0; cf < 4; ++cf) {
            short8 bk = *(const short8*)(&kb[cf * 16 + l15][kw * 8]);
            sacc[cf] = __builtin_amdgcn_mfma_f32_16x16x32_bf16(aq, bk,
                        (floatx4){0.f, 0.f, 0.f, 0.f}, 0, 0, 0);
        }
#pragma unroll
        for (int jj = 0; jj < 4; ++jj) {
            float s0 = sacc[0][jj] * sc + ladj[0][jj];
            float s1 = sacc[1][jj] * sc + ladj[1][jj];
            float s2 = sacc[2][jj] * sc + ladj[2][jj];
            float s3 = sacc[3][jj] * sc + ladj[3][jj];
            float mx = fmaxf(fmaxf(s0, s1), fmaxf(s2, s3));
            mx = fmaxf(mx, __shfl_xor(mx, 1));
            mx = fmaxf(mx, __shfl_xor(mx, 2));
            mx = fmaxf(mx, __shfl_xor(mx, 4));
            mx = fmaxf(mx, __shfl_xor(mx, 8));
            float e0 = __expf(s0 - mx), e1 = __expf(s1 - mx);
            float e2 = __expf(s2 - mx), e3 = __expf(s3 - mx);
            float sum = e0 + e1 + e2 + e3;
            sum += __shfl_xor(sum, 1);
            sum += __shfl_xor(sum, 2);
            sum += __shfl_xor(sum, 4);
            sum += __shfl_xor(sum, 8);
            float inv = 1.f / sum;
            int r = wave * 16 + kw * 4 + jj;
            Pb[r][0 * 16 + l15] = f2u(e0 * inv);
            Pb[r][1 * 16 + l15] = f2u(e1 * inv);
            Pb[r][2 * 16 + l15] = f2u(e2 * inv);
            Pb[r][3 * 16 + l15] = f2u(e3 * inv);
        }
        // Pb is same-wave write->read: no barrier needed.

        // ---- PV: O = P @ V ----
        floatx4 oacc2[2];
#pragma unroll
        for (int cf2 = 0; cf2 < 2; ++cf2) oacc2[cf2] = (floatx4){0.f, 0.f, 0.f, 0.f};
#pragma unroll
        for (int ks = 0; ks < 2; ++ks) {
            short8 ap = *(const short8*)(&Pb[wave * 16 + l15][ks * 32 + kw * 8]);
#pragma unroll
            for (int cf2 = 0; cf2 < 2; ++cf2) {
                short8 bv = *(const short8*)(&Vt[cf2 * 16 + l15][ks * 32 + kw * 8]);
                oacc2[cf2] = __builtin_amdgcn_mfma_f32_16x16x32_bf16(ap, bv, oacc2[cf2], 0, 0, 0);
            }
        }
#pragma unroll
        for (int cf2 = 0; cf2 < 2; ++cf2)
#pragma unroll
            for (int jj = 0; jj < 4; ++jj)
                Ob[wave * 16 + kw * 4 + jj][cf2 * 16 + l15] = f2u(oacc2[cf2][jj]);
        __syncthreads();   // all cross-wave kb/Vt reads done before next head's writes

        // ---- proj accumulate (Ob same-wave; Wpt from L2) ----
        short8 ao = *(const short8*)(&Ob[wave * 16 + l15][kw * 8]);
#pragma unroll
        for (int cf = 0; cf < 16; ++cf) {
            short8 bw = *(const short8*)(Wpt + (size_t)(cf * 16 + l15) * 256 + h * 32 + kw * 8);
            oacc[cf] = __builtin_amdgcn_mfma_f32_16x16x32_bf16(ao, bw, oacc[cf], 0, 0, 0);
        }
    }

    // ---- epilogue: out += oacc * mask[p][row] ----
#pragma unroll
    for (int jj = 0; jj < 4; ++jj) {
        int r = wave * 16 + kw * 4 + jj;
        float mv = mask[p * 64 + r];
#pragma unroll
        for (int cf = 0; cf < 16; ++cf) {
            size_t idx = base + (size_t)r * 256 + cf * 16 + l15;
            out[idx] += oacc[cf][jj] * mv;
        }
    }
}

// ===================== Kernel B: LN2 + MLP (Wbuf-staged) + fused zsum =======
// LDS union: Ybuf (33792) overlaps Hbuf (9216) + Wbuf (20480). No reg cap.
__global__ __launch_bounds__(256) void mlp_mfma_k(
    const float* __restrict__ mask,
    const float* __restrict__ g2, const float* __restrict__ be2,
    const unsigned short* __restrict__ W1t, const float* __restrict__ B1,
    const unsigned short* __restrict__ W2t, const float* __restrict__ B2,
    float* __restrict__ out, float* __restrict__ zsum)
{
    __shared__ __align__(16) unsigned char smem[33792];
    unsigned short (*Ybuf)[264] = (unsigned short (*)[264])smem;      // dead after hoist
    unsigned short (*Hbuf)[72]  = (unsigned short (*)[72])smem;       //  9216
    unsigned short* Wbuf        = (unsigned short*)(smem + 9216);     // 20480

    int w = blockIdx.x, p = w & 31, t = threadIdx.x;
    int wave = t >> 6, lane = t & 63;
    int l15 = lane & 15, kw = lane >> 4;
    size_t base = (size_t)w * 16384;

    for (int it = 0; it < 16; ++it) {
        int r = it * 4 + wave;
        float vals[4]; float sum = 0.f, sq = 0.f;
#pragma unroll
        for (int k2 = 0; k2 < 4; ++k2) {
            float vv = out[base + (size_t)r * 256 + lane + 64 * k2];
            vals[k2] = vv; sum += vv; sq += vv * vv;
        }
        for (int o = 32; o > 0; o >>= 1) { sum += __shfl_xor(sum, o); sq += __shfl_xor(sq, o); }
        float mu = sum * (1.f / 256.f);
        float var = sq * (1.f / 256.f) - mu * mu;
        float rstd = rsqrtf(var + 1e-5f);
#pragma unroll
        for (int k2 = 0; k2 < 4; ++k2) {
            int c = lane + 64 * k2;
            Ybuf[r][c] = f2u((vals[k2] - mu) * rstd * g2[c] + be2[c]);
        }
    }
    __syncthreads();

    short8 ay[8];
#pragma unroll
    for (int ks = 0; ks < 8; ++ks)
        ay[ks] = *(const short8*)(&Ybuf[wave * 16 + l15][ks * 32 + kw * 8]);
    __syncthreads();   // Ybuf dead; Hbuf/Wbuf may now overwrite

    floatx4 oacc[4][4];
#pragma unroll
    for (int m = 0; m < 4; ++m)
#pragma unroll
        for (int j = 0; j < 4; ++j) {
            float bb = B2[wave * 64 + j * 16 + l15];
            oacc[m][j] = (floatx4){bb, bb, bb, bb};
        }

    for (int pass = 0; pass < 16; ++pass) {
        floatx4 facc[4];
#pragma unroll
        for (int j = 0; j < 4; ++j) {
            float bb = B1[pass * 64 + j * 16 + l15];
            facc[j] = (floatx4){bb, bb, bb, bb};
        }
        {
            int nr = t >> 2, c = t & 3;
            *(short8*)(Wbuf + nr * 40 + c * 8) =
                *(const short8*)(W1t + (size_t)(pass * 64 + nr) * 256 + c * 8);
        }
        __syncthreads();
        for (int ks = 0; ks < 8; ++ks) {
            if (ks + 1 < 8) {
                int nr = t >> 2, c = t & 3;
                *(short8*)(Wbuf + ((ks + 1) & 1) * 2560 + nr * 40 + c * 8) =
                    *(const short8*)(W1t + (size_t)(pass * 64 + nr) * 256 + (ks + 1) * 32 + c * 8);
            }
            int hh = (ks & 1) * 2560;
            short8 bf[4];
#pragma unroll
            for (int j = 0; j < 4; ++j)
                bf[j] = *(const short8*)(Wbuf + hh + (j * 16 + l15) * 40 + kw * 8);
#pragma unroll
            for (int j = 0; j < 4; ++j)
                facc[j] = __builtin_amdgcn_mfma_f32_16x16x32_bf16(ay[ks], bf[j], facc[j], 0, 0, 0);
            __syncthreads();
        }
#pragma unroll
        for (int j = 0; j < 4; ++j)
#pragma unroll
            for (int jj = 0; jj < 4; ++jj)
                Hbuf[wave * 16 + kw * 4 + jj][j * 16 + l15] = f2u(gelu_exact(facc[j][jj]));
        __syncthreads();

        for (int ks2 = 0; ks2 < 2; ++ks2) {
            for (int it = 0; it < 4; ++it) {
                int idx = it * 256 + t;
                int nr = idx >> 2, c = idx & 3;
                *(short8*)(Wbuf + nr * 40 + c * 8) =
                    *(const short8*)(W2t + (size_t)nr * 1024 + pass * 64 + ks2 * 32 + c * 8);
            }
            __syncthreads();
            short8 af[4], bf[4];
#pragma unroll
            for (int m = 0; m < 4; ++m)
                af[m] = *(const short8*)(&Hbuf[m * 16 + l15][ks2 * 32 + kw * 8]);
#pragma unroll
            for (int j = 0; j < 4; ++j)
                bf[j] = *(const short8*)(Wbuf + (wave * 64 + j * 16 + l15) * 40 + kw * 8);
#pragma unroll
            for (int m = 0; m < 4; ++m)
#pragma unroll
                for (int j = 0; j < 4; ++j)
                    oacc[m][j] = __builtin_amdgcn_mfma_f32_16x16x32_bf16(af[m], bf[j], oacc[m][j], 0, 0, 0);
            __syncthreads();
        }
    }

    // ---- epilogue: out += oacc * mask; fused masked column-sum -> zsum ----
    float zp[4] = {0.f, 0.f, 0.f, 0.f};
#pragma unroll
    for (int m = 0; m < 4; ++m) {
#pragma unroll
        for (int jj = 0; jj < 4; ++jj) {
            int r = m * 16 + kw * 4 + jj;
            float mv = mask[p * 64 + r];
#pragma unroll
            for (int j = 0; j < 4; ++j) {
                size_t idx = base + (size_t)r * 256 + wave * 64 + j * 16 + l15;
                float nv = out[idx] + oacc[m][j][jj] * mv;
                out[idx] = nv;
                zp[j] += mv * nv;
            }
        }
    }
#pragma unroll
    for (int j = 0; j < 4; ++j) {
        zp[j] += __shfl_xor(zp[j], 16);
        zp[j] += __shfl_xor(zp[j], 32);
    }
    if (kw == 0) {
#pragma unroll
        for (int j = 0; j < 4; ++j)
            zsum[(size_t)w * 256 + wave * 64 + j * 16 + l15] = zp[j];
    }
}

// ===================== Kernel Z2: pool-finish + LN + z attn + MLP ===========
__global__ __launch_bounds__(256) void zcompute_k(
    const float* __restrict__ zsum, const float* __restrict__ mask,
    const float* __restrict__ gvec, const float* __restrict__ bvec,
    const unsigned short* __restrict__ bWqkvt, const float* __restrict__ Bqkv,
    const unsigned short* __restrict__ bWpt, const float* __restrict__ Bp,
    const unsigned short* __restrict__ bW1t, const float* __restrict__ B1,
    const unsigned short* __restrict__ bW2t, const float* __restrict__ B2,
    float* __restrict__ zout)
{
    __shared__ unsigned short Zbuf[32][264];
    __shared__ unsigned short Z2[32][264];
    __shared__ unsigned short qb[32][40], kb[32][40], Vt[32][40], Pb[32][40], Ob[32][40];
    __shared__ unsigned short Hbuf[32][72];
    __shared__ float msh[32];
    int bt = blockIdx.x, t = threadIdx.x;
    int wave = t >> 6, lane = t & 63;
    int l15 = lane & 15, kw = lane >> 4;
    int rt = wave & 1, cq = wave >> 1;

    if (t < 32) {
        float s = 0.f;
        for (int nn = 0; nn < 64; ++nn) s += mask[t * 64 + nn];
        msh[t] = fmaxf(s, 1.f);
    }
    __syncthreads();

    for (int it = 0; it < 8; ++it) {
        int r = it * 4 + wave;
        float inv_m = 1.f / msh[r];
        float vals[4]; float sum = 0.f, sq = 0.f;
#pragma unroll
        for (int k2 = 0; k2 < 4; ++k2) {
            float vv = zsum[(size_t)bt * 8192 + (size_t)r * 256 + lane + 64 * k2] * inv_m;
            vals[k2] = vv; sum += vv; sq += vv * vv;
        }
        for (int o = 32; o > 0; o >>= 1) { sum += __shfl_xor(sum, o); sq += __shfl_xor(sq, o); }
        float mu = sum * (1.f / 256.f);
        float var = sq * (1.f / 256.f) - mu * mu;
        float rstd = rsqrtf(var + 1e-5f);
#pragma unroll
        for (int k2 = 0; k2 < 4; ++k2) {
            int c = lane + 64 * k2;
            Zbuf[r][c] = f2u((vals[k2] - mu) * rstd * gvec[c] + bvec[c]);
        }
    }
    __syncthreads();

    short8 ay[8];
#pragma unroll
    for (int ks = 0; ks < 8; ++ks)
        ay[ks] = *(const short8*)(&Zbuf[rt * 16 + l15][ks * 32 + kw * 8]);

    floatx4 pacc[8];
#pragma unroll
    for (int cf = 0; cf < 8; ++cf) {
        float bb = Bp[cq * 128 + cf * 16 + l15];
        pacc[cf] = (floatx4){bb, bb, bb, bb};
    }
    const float sc = 0.17677669529663689f;

    for (int h = 0; h < 8; ++h) {
        floatx4 qacc[3];
#pragma unroll
        for (int cf = 0; cf < 3; ++cf) {
            int c96 = cq * 48 + cf * 16 + l15;
            int gcol = (c96 >> 5) * 256 + h * 32 + (c96 & 31);
            float bb = Bqkv[gcol];
            qacc[cf] = (floatx4){bb, bb, bb, bb};
        }
#pragma unroll
        for (int ks = 0; ks < 8; ++ks) {
#pragma unroll
            for (int cf = 0; cf < 3; ++cf) {
                int c96 = cq * 48 + cf * 16 + l15;
                int gcol = (c96 >> 5) * 256 + h * 32 + (c96 & 31);
                short8 bw = *(const short8*)(bWqkvt + (size_t)gcol * 256 + ks * 32 + kw * 8);
                qacc[cf] = __builtin_amdgcn_mfma_f32_16x16x32_bf16(ay[ks], bw, qacc[cf], 0, 0, 0);
            }
        }
#pragma unroll
        for (int cf = 0; cf < 3; ++cf) {
            int c96 = cq * 48 + cf * 16 + l15;
            int which = c96 >> 5, d = c96 & 31;
#pragma unroll
            for (int jj = 0; jj < 4; ++jj) {
                int r = rt * 16 + kw * 4 + jj;
                unsigned short ub = f2u(qacc[cf][jj]);
                if (which == 0) qb[r][d] = ub;
                else if (which == 1) kb[r][d] = ub;
                else Vt[d][r] = ub;
            }
        }
        __syncthreads();
        if (wave < 2) {
            short8 aq = *(const short8*)(&qb[wave * 16 + l15][kw * 8]);
            floatx4 sacc[2];
#pragma unroll
            for (int cf = 0; cf < 2; ++cf) {
                short8 bk = *(const short8*)(&kb[cf * 16 + l15][kw * 8]);
                sacc[cf] = __builtin_amdgcn_mfma_f32_16x16x32_bf16(aq, bk,
                            (floatx4){0.f, 0.f, 0.f, 0.f}, 0, 0, 0);
            }
#pragma unroll
            for (int jj = 0; jj < 4; ++jj) {
                float s0 = sacc[0][jj] * sc;
                float s1 = sacc[1][jj] * sc;
                float mx = fmaxf(s0, s1);
                mx = fmaxf(mx, __shfl_xor(mx, 1));
                mx = fmaxf(mx, __shfl_xor(mx, 2));
                mx = fmaxf(mx, __shfl_xor(mx, 4));
                mx = fmaxf(mx, __shfl_xor(mx, 8));
                float e0 = __expf(s0 - mx), e1 = __expf(s1 - mx);
                float sum = e0 + e1;
                sum += __shfl_xor(sum, 1);
                sum += __shfl_xor(sum, 2);
                sum += __shfl_xor(sum, 4);
                sum += __shfl_xor(sum, 8);
                float inv = 1.f / sum;
                int r = wave * 16 + kw * 4 + jj;
                Pb[r][l15] = f2u(e0 * inv);
                Pb[r][16 + l15] = f2u(e1 * inv);
            }
        }
        __syncthreads();
        {
            short8 ap = *(const short8*)(&Pb[rt * 16 + l15][kw * 8]);
            short8 bv = *(const short8*)(&Vt[cq * 16 + l15][kw * 8]);
            floatx4 oo = __builtin_amdgcn_mfma_f32_16x16x32_bf16(ap, bv,
                          (floatx4){0.f, 0.f, 0.f, 0.f}, 0, 0, 0);
#pragma unroll
            for (int jj = 0; jj < 4; ++jj)
                Ob[rt * 16 + kw * 4 + jj][cq * 16 + l15] = f2u(oo[jj]);
        }
        __syncthreads();
        {
            short8 ao = *(const short8*)(&Ob[rt * 16 + l15][kw * 8]);
#pragma unroll
            for (int cf = 0; cf < 8; ++cf) {
                int gcol = cq * 128 + cf * 16 + l15;
                short8 bw = *(const short8*)(bWpt + (size_t)gcol * 256 + h * 32 + kw * 8);
                pacc[cf] = __builtin_amdgcn_mfma_f32_16x16x32_bf16(ao, bw, pacc[cf], 0, 0, 0);
            }
        }
        __syncthreads();
    }
#pragma unroll
    for (int cf = 0; cf < 8; ++cf)
#pragma unroll
        for (int jj = 0; jj < 4; ++jj)
            Z2[rt * 16 + kw * 4 + jj][cq * 128 + cf * 16 + l15] = f2u(pacc[cf][jj]);
    __syncthreads();

    short8 az[8];
#pragma unroll
    for (int ks = 0; ks < 8; ++ks)
        az[ks] = *(const short8*)(&Z2[rt * 16 + l15][ks * 32 + kw * 8]);

    floatx4 oacc2[8];
#pragma unroll
    for (int cf = 0; cf < 8; ++cf) {
        float bb = B2[cq * 128 + cf * 16 + l15];
        oacc2[cf] = (floatx4){bb, bb, bb, bb};
    }
    for (int pass = 0; pass < 16; ++pass) {
        floatx4 facc[2];
#pragma unroll
        for (int cf = 0; cf < 2; ++cf) {
            int col = pass * 64 + cq * 32 + cf * 16 + l15;
            float bb = B1[col];
            facc[cf] = (floatx4){bb, bb, bb, bb};
        }
#pragma unroll
        for (int ks = 0; ks < 8; ++ks) {
#pragma unroll
            for (int cf = 0; cf < 2; ++cf) {
                int col = pass * 64 + cq * 32 + cf * 16 + l15;
                short8 bw = *(const short8*)(bW1t + (size_t)col * 256 + ks * 32 + kw * 8);
                facc[cf] = __builtin_amdgcn_mfma_f32_16x16x32_bf16(az[ks], bw, facc[cf], 0, 0, 0);
            }
        }
#pragma unroll
        for (int cf = 0; cf < 2; ++cf)
#pragma unroll
            for (int jj = 0; jj < 4; ++jj)
                Hbuf[rt * 16 + kw * 4 + jj][cq * 32 + cf * 16 + l15] = f2u(gelu_exact(facc[cf][jj]));
        __syncthreads();
#pragma unroll
        for (int ks = 0; ks < 2; ++ks) {
            short8 ah = *(const short8*)(&Hbuf[rt * 16 + l15][ks * 32 + kw * 8]);
#pragma unroll
            for (int cf = 0; cf < 8; ++cf) {
                int gcol = cq * 128 + cf * 16 + l15;
                short8 bw = *(const short8*)(bW2t + (size_t)gcol * 1024 + pass * 64 + ks * 32 + kw * 8);
                oacc2[cf] = __builtin_amdgcn_mfma_f32_16x16x32_bf16(ah, bw, oacc2[cf], 0, 0, 0);
            }
        }
        __syncthreads();
    }
#pragma unroll
    for (int cf = 0; cf < 8; ++cf)
#pragma unroll
        for (int jj = 0; jj < 4; ++jj) {
            int r = rt * 16 + kw * 4 + jj;
            int c = cq * 128 + cf * 16 + l15;
            zout[(size_t)bt * 8192 + r * 256 + c] = oacc2[cf][jj];
        }
}

// ===================== Kernel Z3: broadcast add over N ======================
__global__ __launch_bounds__(256) void zadd_k(
    const float* __restrict__ zout, float* __restrict__ out)
{
    int w = blockIdx.x, t = threadIdx.x;
    size_t base = (size_t)w * 16384;
    float zv = zout[(size_t)w * 256 + t];
    for (int nn = 0; nn < 64; ++nn)
        out[base + (size_t)nn * 256 + t] += zv;
}

extern "C" void kernel_launch(void* const* d_in, const int* in_sizes, int n_in,
                              void* d_out, int out_size, void* d_ws, size_t ws_size,
                              hipStream_t stream) {
    (void)in_sizes; (void)n_in; (void)out_size; (void)ws_size;
    const float* x        = (const float*)d_in[0];
    const float* mask     = (const float*)d_in[1];
    const float* adj      = (const float*)d_in[2];
    const float* dn1_g    = (const float*)d_in[3];
    const float* dn1_b    = (const float*)d_in[4];
    const float* dn2_g    = (const float*)d_in[5];
    const float* dn2_b    = (const float*)d_in[6];
    const float* bn1_g    = (const float*)d_in[7];
    const float* bn1_b    = (const float*)d_in[8];
    const float* d_qkv_w  = (const float*)d_in[9];
    const float* d_qkv_b  = (const float*)d_in[10];
    const float* d_proj_w = (const float*)d_in[11];
    const float* d_proj_b = (const float*)d_in[12];
    const float* d_fc1_w  = (const float*)d_in[13];
    const float* d_fc1_b  = (const float*)d_in[14];
    const float* d_fc2_w  = (const float*)d_in[15];
    const float* d_fc2_b  = (const float*)d_in[16];
    const float* b_qkv_w  = (const float*)d_in[17];
    const float* b_qkv_b  = (const float*)d_in[18];
    const float* b_proj_w = (const float*)d_in[19];
    const float* b_proj_b = (const float*)d_in[20];
    const float* b_fc1_w  = (const float*)d_in[21];
    const float* b_fc1_b  = (const float*)d_in[22];
    const float* b_fc2_w  = (const float*)d_in[23];
    const float* b_fc2_b  = (const float*)d_in[24];
    float* out = (float*)d_out;

    // workspace (shorts unless noted), ~5.1 MB total:
    // W1t 262144 | W2t 262144 | Wqkvt 196608 | Wpt 65536
    // bW1t 262144 | bW2t 262144 | bWqkvt 196608 | bWpt 65536
    // zsum fp32 262144 | zout fp32 262144
    unsigned short* W1t    = (unsigned short*)d_ws;
    unsigned short* W2t    = W1t + 262144;
    unsigned short* Wqkvt  = W2t + 262144;
    unsigned short* Wpt    = Wqkvt + 196608;
    unsigned short* bW1t   = Wpt + 65536;
    unsigned short* bW2t   = bW1t + 262144;
    unsigned short* bWqkvt = bW2t + 262144;
    unsigned short* bWpt   = bWqkvt + 196608;
    float* zsum            = (float*)(bWpt + 65536);
    float* zout            = zsum + 262144;

    pack_weights_k<<<4608, 256, 0, stream>>>(d_fc1_w, d_fc2_w, d_qkv_w, d_proj_w,
                                             b_fc1_w, b_fc2_w, b_qkv_w, b_proj_w,
                                             W1t, W2t, Wqkvt, Wpt,
                                             bW1t, bW2t, bWqkvt, bWpt);
    attn_mfma_k<<<1024, 256, 0, stream>>>(x, mask, adj, dn1_g, dn1_b,
                                          Wqkvt, d_qkv_b, Wpt, d_proj_b, out);
    mlp_mfma_k<<<1024, 256, 0, stream>>>(mask, dn2_g, dn2_b,
                                         W1t, d_fc1_b, W2t, d_fc2_b, out, zsum);
    zcompute_k<<<32, 256, 0, stream>>>(zsum, mask, bn1_g, bn1_b,
                                       bWqkvt, b_qkv_b, bWpt, b_proj_b,
                                       bW1t, b_fc1_b, bW2t, b_fc2_b, zout);
    zadd_k<<<1024, 256, 0, stream>>>(zout, out);
}

// Round 7
// 827.122 us; speedup vs baseline: 1.3044x; 1.0904x over previous
//
#include <hip/hip_runtime.h>
#include <hip/hip_bf16.h>
#include <math.h>

typedef __attribute__((ext_vector_type(8))) short short8;
typedef __attribute__((ext_vector_type(4))) float floatx4;

__device__ __forceinline__ unsigned short f2u(float f) {
    union { float f; unsigned int i; } c; c.f = f;
    unsigned int r = c.i + 0x7FFF + ((c.i >> 16) & 1);   // round-to-nearest-even
    return (unsigned short)(r >> 16);
}
__device__ __forceinline__ float gelu_exact(float x) {
    return 0.5f * x * (1.0f + erff(x * 0.7071067811865475f));
}

// ===================== Kernel P: pack weights bf16 k-contig + Ladj table ===
__global__ __launch_bounds__(256) void pack_weights_k(
    const float* __restrict__ W1, const float* __restrict__ W2,
    const float* __restrict__ Wqkv, const float* __restrict__ Wp,
    const float* __restrict__ bW1, const float* __restrict__ bW2,
    const float* __restrict__ bWqkv, const float* __restrict__ bWp,
    const float* __restrict__ adj,
    unsigned short* __restrict__ W1t, unsigned short* __restrict__ W2t,
    unsigned short* __restrict__ Wqkvt, unsigned short* __restrict__ Wpt,
    unsigned short* __restrict__ bW1t, unsigned short* __restrict__ bW2t,
    unsigned short* __restrict__ bWqkvt, unsigned short* __restrict__ bWpt,
    float* __restrict__ Ladj)
{
    int b = blockIdx.x, t = threadIdx.x;
    if (b < 1024) {
        W1t[(size_t)b * 256 + t] = f2u(W1[(size_t)t * 1024 + b]);
    } else if (b < 1280) {
        int n = b - 1024;
        for (int it = 0; it < 4; ++it) {
            int k = it * 256 + t;
            W2t[(size_t)n * 1024 + k] = f2u(W2[(size_t)k * 256 + n]);
        }
    } else if (b < 2048) {
        int c = b - 1280;
        Wqkvt[(size_t)c * 256 + t] = f2u(Wqkv[(size_t)t * 768 + c]);
    } else if (b < 2304) {
        int c = b - 2048;
        Wpt[(size_t)c * 256 + t] = f2u(Wp[(size_t)t * 256 + c]);
    } else if (b < 3328) {
        int c = b - 2304;
        bW1t[(size_t)c * 256 + t] = f2u(bW1[(size_t)t * 1024 + c]);
    } else if (b < 3584) {
        int n = b - 3328;
        for (int it = 0; it < 4; ++it) {
            int k = it * 256 + t;
            bW2t[(size_t)n * 1024 + k] = f2u(bW2[(size_t)k * 256 + n]);
        }
    } else if (b < 4352) {
        int c = b - 3584;
        bWqkvt[(size_t)c * 256 + t] = f2u(bWqkv[(size_t)t * 768 + c]);
    } else if (b < 4608) {
        int c = b - 4352;
        bWpt[(size_t)c * 256 + t] = f2u(bWp[(size_t)t * 256 + c]);
    } else {
        for (int i = 0; i < 16; ++i) {
            int idx = t * 16 + i;
            Ladj[idx] = logf(adj[idx] + 1e-6f);
        }
    }
}

// ===================== Kernel A: LN1 + window attention (MFMA) =============
// LDS union: Ybuf[64][264] (33792 B) overlaps attention buffers (29184 B).
// __launch_bounds__(256,2): 256-total-reg budget -> 2 waves/SIMD (R3-proven;
// R6 showed uncapped -> 140 VGPR + AGPR > 256 -> 1 wave/SIMD, 12% occ).
// Ladj precomputed (saves 16 regs + 16 logf/lane). 2 barriers per head.
__global__ __launch_bounds__(256, 2) void attn_mfma_k(
    const float* __restrict__ x, const float* __restrict__ mask,
    const float* __restrict__ Ladj,
    const float* __restrict__ g1, const float* __restrict__ be1,
    const unsigned short* __restrict__ Wqkvt, const float* __restrict__ Bqkv,
    const unsigned short* __restrict__ Wpt, const float* __restrict__ Bp,
    float* __restrict__ out)
{
    __shared__ __align__(16) unsigned char smem[33792];
    unsigned short (*Ybuf)[264] = (unsigned short (*)[264])smem;           // dead after hoist
    unsigned short (*qb)[40]    = (unsigned short (*)[40])(smem);          //  5120
    unsigned short (*kb)[40]    = (unsigned short (*)[40])(smem + 5120);   //  5120
    unsigned short (*Vt)[72]    = (unsigned short (*)[72])(smem + 10240);  //  4608
    unsigned short (*Pb)[72]    = (unsigned short (*)[72])(smem + 14848);  //  9216
    unsigned short (*Ob)[40]    = (unsigned short (*)[40])(smem + 24064);  //  5120

    int w = blockIdx.x, p = w & 31, t = threadIdx.x;
    int wave = t >> 6, lane = t & 63;
    int l15 = lane & 15, kw = lane >> 4;
    size_t base = (size_t)w * 16384;

    // ---- LN1 -> bf16 Ybuf; out = x (residual init) ----
    for (int it = 0; it < 16; ++it) {
        int r = it * 4 + wave;
        float vals[4]; float sum = 0.f, sq = 0.f;
#pragma unroll
        for (int k2 = 0; k2 < 4; ++k2) {
            float vv = x[base + (size_t)r * 256 + lane + 64 * k2];
            vals[k2] = vv; sum += vv; sq += vv * vv;
        }
        for (int o = 32; o > 0; o >>= 1) { sum += __shfl_xor(sum, o); sq += __shfl_xor(sq, o); }
        float mu = sum * (1.f / 256.f);
        float var = sq * (1.f / 256.f) - mu * mu;
        float rstd = rsqrtf(var + 1e-5f);
#pragma unroll
        for (int k2 = 0; k2 < 4; ++k2) {
            int c = lane + 64 * k2;
            Ybuf[r][c] = f2u((vals[k2] - mu) * rstd * g1[c] + be1[c]);
            out[base + (size_t)r * 256 + c] = vals[k2];
        }
    }
    __syncthreads();

    // ---- hoist this wave's Y A-fragments into registers ----
    short8 ay[8];
#pragma unroll
    for (int ks = 0; ks < 8; ++ks)
        ay[ks] = *(const short8*)(&Ybuf[wave * 16 + l15][ks * 32 + kw * 8]);

    floatx4 oacc[16];
#pragma unroll
    for (int cf = 0; cf < 16; ++cf) {
        float bb = Bp[cf * 16 + l15];
        oacc[cf] = (floatx4){bb, bb, bb, bb};
    }
    __syncthreads();   // Ybuf reads complete before qb/kb/Vt overlap-writes

    const float sc = 0.17677669529663689f;

    for (int h = 0; h < 8; ++h) {
        // ---- QKV GEMM (B-frags direct from L2-resident packed weights) ----
        floatx4 qacc[6];
#pragma unroll
        for (int cf = 0; cf < 6; ++cf) {
            int gcol = (cf >> 1) * 256 + h * 32 + (cf & 1) * 16 + l15;
            float bb = Bqkv[gcol];
            qacc[cf] = (floatx4){bb, bb, bb, bb};
        }
#pragma unroll
        for (int ks = 0; ks < 8; ++ks) {
            short8 bw[6];
#pragma unroll
            for (int cf = 0; cf < 6; ++cf) {
                int gcol = (cf >> 1) * 256 + h * 32 + (cf & 1) * 16 + l15;
                bw[cf] = *(const short8*)(Wqkvt + (size_t)gcol * 256 + ks * 32 + kw * 8);
            }
#pragma unroll
            for (int cf = 0; cf < 6; ++cf)
                qacc[cf] = __builtin_amdgcn_mfma_f32_16x16x32_bf16(ay[ks], bw[cf], qacc[cf], 0, 0, 0);
        }
#pragma unroll
        for (int cf = 0; cf < 6; ++cf)
#pragma unroll
            for (int jj = 0; jj < 4; ++jj) {
                int r = wave * 16 + kw * 4 + jj;
                int d = (cf & 1) * 16 + l15;
                unsigned short ub = f2u(qacc[cf][jj]);
                if (cf < 2) qb[r][d] = ub;
                else if (cf < 4) kb[r][d] = ub;
                else Vt[d][r] = ub;
            }
        __syncthreads();   // kb/Vt ready for cross-wave reads

        // ---- scores S = Q K^T + in-register softmax (Ladj from L2) ----
        short8 aq = *(const short8*)(&qb[wave * 16 + l15][kw * 8]);
        floatx4 sacc[4];
#pragma unroll
        for (int cf = 0; cf < 4; ++cf) {
            short8 bk = *(const short8*)(&kb[cf * 16 + l15][kw * 8]);
            sacc[cf] = __builtin_amdgcn_mfma_f32_16x16x32_bf16(aq, bk,
                        (floatx4){0.f, 0.f, 0.f, 0.f}, 0, 0, 0);
        }
#pragma unroll
        for (int jj = 0; jj < 4; ++jj) {
            int r = wave * 16 + kw * 4 + jj;
            float s0 = sacc[0][jj] * sc + Ladj[r * 64 + 0 * 16 + l15];
            float s1 = sacc[1][jj] * sc + Ladj[r * 64 + 1 * 16 + l15];
            float s2 = sacc[2][jj] * sc + Ladj[r * 64 + 2 * 16 + l15];
            float s3 = sacc[3][jj] * sc + Ladj[r * 64 + 3 * 16 + l15];
            float mx = fmaxf(fmaxf(s0, s1), fmaxf(s2, s3));
            mx = fmaxf(mx, __shfl_xor(mx, 1));
            mx = fmaxf(mx, __shfl_xor(mx, 2));
            mx = fmaxf(mx, __shfl_xor(mx, 4));
            mx = fmaxf(mx, __shfl_xor(mx, 8));
            float e0 = __expf(s0 - mx), e1 = __expf(s1 - mx);
            float e2 = __expf(s2 - mx), e3 = __expf(s3 - mx);
            float sum = e0 + e1 + e2 + e3;
            sum += __shfl_xor(sum, 1);
            sum += __shfl_xor(sum, 2);
            sum += __shfl_xor(sum, 4);
            sum += __shfl_xor(sum, 8);
            float inv = 1.f / sum;
            Pb[r][0 * 16 + l15] = f2u(e0 * inv);
            Pb[r][1 * 16 + l15] = f2u(e1 * inv);
            Pb[r][2 * 16 + l15] = f2u(e2 * inv);
            Pb[r][3 * 16 + l15] = f2u(e3 * inv);
        }
        // Pb is same-wave write->read: no barrier needed.

        // ---- PV: O = P @ V ----
        floatx4 oacc2[2];
#pragma unroll
        for (int cf2 = 0; cf2 < 2; ++cf2) oacc2[cf2] = (floatx4){0.f, 0.f, 0.f, 0.f};
#pragma unroll
        for (int ks = 0; ks < 2; ++ks) {
            short8 ap = *(const short8*)(&Pb[wave * 16 + l15][ks * 32 + kw * 8]);
#pragma unroll
            for (int cf2 = 0; cf2 < 2; ++cf2) {
                short8 bv = *(const short8*)(&Vt[cf2 * 16 + l15][ks * 32 + kw * 8]);
                oacc2[cf2] = __builtin_amdgcn_mfma_f32_16x16x32_bf16(ap, bv, oacc2[cf2], 0, 0, 0);
            }
        }
#pragma unroll
        for (int cf2 = 0; cf2 < 2; ++cf2)
#pragma unroll
            for (int jj = 0; jj < 4; ++jj)
                Ob[wave * 16 + kw * 4 + jj][cf2 * 16 + l15] = f2u(oacc2[cf2][jj]);
        __syncthreads();   // all cross-wave kb/Vt reads done before next head's writes

        // ---- proj accumulate (Ob same-wave; Wpt from L2) ----
        short8 ao = *(const short8*)(&Ob[wave * 16 + l15][kw * 8]);
#pragma unroll
        for (int cf = 0; cf < 16; ++cf) {
            short8 bw = *(const short8*)(Wpt + (size_t)(cf * 16 + l15) * 256 + h * 32 + kw * 8);
            oacc[cf] = __builtin_amdgcn_mfma_f32_16x16x32_bf16(ao, bw, oacc[cf], 0, 0, 0);
        }
    }

    // ---- epilogue: out += oacc * mask[p][row] ----
#pragma unroll
    for (int jj = 0; jj < 4; ++jj) {
        int r = wave * 16 + kw * 4 + jj;
        float mv = mask[p * 64 + r];
#pragma unroll
        for (int cf = 0; cf < 16; ++cf) {
            size_t idx = base + (size_t)r * 256 + cf * 16 + l15;
            out[idx] += oacc[cf][jj] * mv;
        }
    }
}

// ===================== Kernel B: LN2 + MLP (Wbuf-staged) + fused zsum =======
// LDS union: Ybuf (33792) overlaps Hbuf (9216) + Wbuf (20480). (256,2) cap.
__global__ __launch_bounds__(256, 2) void mlp_mfma_k(
    const float* __restrict__ mask,
    const float* __restrict__ g2, const float* __restrict__ be2,
    const unsigned short* __restrict__ W1t, const float* __restrict__ B1,
    const unsigned short* __restrict__ W2t, const float* __restrict__ B2,
    float* __restrict__ out, float* __restrict__ zsum)
{
    __shared__ __align__(16) unsigned char smem[33792];
    unsigned short (*Ybuf)[264] = (unsigned short (*)[264])smem;      // dead after hoist
    unsigned short (*Hbuf)[72]  = (unsigned short (*)[72])smem;       //  9216
    unsigned short* Wbuf        = (unsigned short*)(smem + 9216);     // 20480

    int w = blockIdx.x, p = w & 31, t = threadIdx.x;
    int wave = t >> 6, lane = t & 63;
    int l15 = lane & 15, kw = lane >> 4;
    size_t base = (size_t)w * 16384;

    for (int it = 0; it < 16; ++it) {
        int r = it * 4 + wave;
        float vals[4]; float sum = 0.f, sq = 0.f;
#pragma unroll
        for (int k2 = 0; k2 < 4; ++k2) {
            float vv = out[base + (size_t)r * 256 + lane + 64 * k2];
            vals[k2] = vv; sum += vv; sq += vv * vv;
        }
        for (int o = 32; o > 0; o >>= 1) { sum += __shfl_xor(sum, o); sq += __shfl_xor(sq, o); }
        float mu = sum * (1.f / 256.f);
        float var = sq * (1.f / 256.f) - mu * mu;
        float rstd = rsqrtf(var + 1e-5f);
#pragma unroll
        for (int k2 = 0; k2 < 4; ++k2) {
            int c = lane + 64 * k2;
            Ybuf[r][c] = f2u((vals[k2] - mu) * rstd * g2[c] + be2[c]);
        }
    }
    __syncthreads();

    short8 ay[8];
#pragma unroll
    for (int ks = 0; ks < 8; ++ks)
        ay[ks] = *(const short8*)(&Ybuf[wave * 16 + l15][ks * 32 + kw * 8]);
    __syncthreads();   // Ybuf dead; Hbuf/Wbuf may now overwrite

    floatx4 oacc[4][4];
#pragma unroll
    for (int m = 0; m < 4; ++m)
#pragma unroll
        for (int j = 0; j < 4; ++j) {
            float bb = B2[wave * 64 + j * 16 + l15];
            oacc[m][j] = (floatx4){bb, bb, bb, bb};
        }

    for (int pass = 0; pass < 16; ++pass) {
        floatx4 facc[4];
#pragma unroll
        for (int j = 0; j < 4; ++j) {
            float bb = B1[pass * 64 + j * 16 + l15];
            facc[j] = (floatx4){bb, bb, bb, bb};
        }
        {
            int nr = t >> 2, c = t & 3;
            *(short8*)(Wbuf + nr * 40 + c * 8) =
                *(const short8*)(W1t + (size_t)(pass * 64 + nr) * 256 + c * 8);
        }
        __syncthreads();
        for (int ks = 0; ks < 8; ++ks) {
            if (ks + 1 < 8) {
                int nr = t >> 2, c = t & 3;
                *(short8*)(Wbuf + ((ks + 1) & 1) * 2560 + nr * 40 + c * 8) =
                    *(const short8*)(W1t + (size_t)(pass * 64 + nr) * 256 + (ks + 1) * 32 + c * 8);
            }
            int hh = (ks & 1) * 2560;
            short8 bf[4];
#pragma unroll
            for (int j = 0; j < 4; ++j)
                bf[j] = *(const short8*)(Wbuf + hh + (j * 16 + l15) * 40 + kw * 8);
#pragma unroll
            for (int j = 0; j < 4; ++j)
                facc[j] = __builtin_amdgcn_mfma_f32_16x16x32_bf16(ay[ks], bf[j], facc[j], 0, 0, 0);
            __syncthreads();
        }
#pragma unroll
        for (int j = 0; j < 4; ++j)
#pragma unroll
            for (int jj = 0; jj < 4; ++jj)
                Hbuf[wave * 16 + kw * 4 + jj][j * 16 + l15] = f2u(gelu_exact(facc[j][jj]));
        __syncthreads();

        for (int ks2 = 0; ks2 < 2; ++ks2) {
            for (int it = 0; it < 4; ++it) {
                int idx = it * 256 + t;
                int nr = idx >> 2, c = idx & 3;
                *(short8*)(Wbuf + nr * 40 + c * 8) =
                    *(const short8*)(W2t + (size_t)nr * 1024 + pass * 64 + ks2 * 32 + c * 8);
            }
            __syncthreads();
            short8 af[4], bf[4];
#pragma unroll
            for (int m = 0; m < 4; ++m)
                af[m] = *(const short8*)(&Hbuf[m * 16 + l15][ks2 * 32 + kw * 8]);
#pragma unroll
            for (int j = 0; j < 4; ++j)
                bf[j] = *(const short8*)(Wbuf + (wave * 64 + j * 16 + l15) * 40 + kw * 8);
#pragma unroll
            for (int m = 0; m < 4; ++m)
#pragma unroll
                for (int j = 0; j < 4; ++j)
                    oacc[m][j] = __builtin_amdgcn_mfma_f32_16x16x32_bf16(af[m], bf[j], oacc[m][j], 0, 0, 0);
            __syncthreads();
        }
    }

    // ---- epilogue: out += oacc * mask; fused masked column-sum -> zsum ----
    float zp[4] = {0.f, 0.f, 0.f, 0.f};
#pragma unroll
    for (int m = 0; m < 4; ++m) {
#pragma unroll
        for (int jj = 0; jj < 4; ++jj) {
            int r = m * 16 + kw * 4 + jj;
            float mv = mask[p * 64 + r];
#pragma unroll
            for (int j = 0; j < 4; ++j) {
                size_t idx = base + (size_t)r * 256 + wave * 64 + j * 16 + l15;
                float nv = out[idx] + oacc[m][j][jj] * mv;
                out[idx] = nv;
                zp[j] += mv * nv;
            }
        }
    }
#pragma unroll
    for (int j = 0; j < 4; ++j) {
        zp[j] += __shfl_xor(zp[j], 16);
        zp[j] += __shfl_xor(zp[j], 32);
    }
    if (kw == 0) {
#pragma unroll
        for (int j = 0; j < 4; ++j)
            zsum[(size_t)w * 256 + wave * 64 + j * 16 + l15] = zp[j];
    }
}

// ===================== Kernel Z2: pool-finish + LN + z attn + MLP ===========
__global__ __launch_bounds__(256) void zcompute_k(
    const float* __restrict__ zsum, const float* __restrict__ mask,
    const float* __restrict__ gvec, const float* __restrict__ bvec,
    const unsigned short* __restrict__ bWqkvt, const float* __restrict__ Bqkv,
    const unsigned short* __restrict__ bWpt, const float* __restrict__ Bp,
    const unsigned short* __restrict__ bW1t, const float* __restrict__ B1,
    const unsigned short* __restrict__ bW2t, const float* __restrict__ B2,
    float* __restrict__ zout)
{
    __shared__ unsigned short Zbuf[32][264];
    __shared__ unsigned short Z2[32][264];
    __shared__ unsigned short qb[32][40], kb[32][40], Vt[32][40], Pb[32][40], Ob[32][40];
    __shared__ unsigned short Hbuf[32][72];
    __shared__ float msh[32];
    int bt = blockIdx.x, t = threadIdx.x;
    int wave = t >> 6, lane = t & 63;
    int l15 = lane & 15, kw = lane >> 4;
    int rt = wave & 1, cq = wave >> 1;

    if (t < 32) {
        float s = 0.f;
        for (int nn = 0; nn < 64; ++nn) s += mask[t * 64 + nn];
        msh[t] = fmaxf(s, 1.f);
    }
    __syncthreads();

    for (int it = 0; it < 8; ++it) {
        int r = it * 4 + wave;
        float inv_m = 1.f / msh[r];
        float vals[4]; float sum = 0.f, sq = 0.f;
#pragma unroll
        for (int k2 = 0; k2 < 4; ++k2) {
            float vv = zsum[(size_t)bt * 8192 + (size_t)r * 256 + lane + 64 * k2] * inv_m;
            vals[k2] = vv; sum += vv; sq += vv * vv;
        }
        for (int o = 32; o > 0; o >>= 1) { sum += __shfl_xor(sum, o); sq += __shfl_xor(sq, o); }
        float mu = sum * (1.f / 256.f);
        float var = sq * (1.f / 256.f) - mu * mu;
        float rstd = rsqrtf(var + 1e-5f);
#pragma unroll
        for (int k2 = 0; k2 < 4; ++k2) {
            int c = lane + 64 * k2;
            Zbuf[r][c] = f2u((vals[k2] - mu) * rstd * gvec[c] + bvec[c]);
        }
    }
    __syncthreads();

    short8 ay[8];
#pragma unroll
    for (int ks = 0; ks < 8; ++ks)
        ay[ks] = *(const short8*)(&Zbuf[rt * 16 + l15][ks * 32 + kw * 8]);

    floatx4 pacc[8];
#pragma unroll
    for (int cf = 0; cf < 8; ++cf) {
        float bb = Bp[cq * 128 + cf * 16 + l15];
        pacc[cf] = (floatx4){bb, bb, bb, bb};
    }
    const float sc = 0.17677669529663689f;

    for (int h = 0; h < 8; ++h) {
        floatx4 qacc[3];
#pragma unroll
        for (int cf = 0; cf < 3; ++cf) {
            int c96 = cq * 48 + cf * 16 + l15;
            int gcol = (c96 >> 5) * 256 + h * 32 + (c96 & 31);
            float bb = Bqkv[gcol];
            qacc[cf] = (floatx4){bb, bb, bb, bb};
        }
#pragma unroll
        for (int ks = 0; ks < 8; ++ks) {
#pragma unroll
            for (int cf = 0; cf < 3; ++cf) {
                int c96 = cq * 48 + cf * 16 + l15;
                int gcol = (c96 >> 5) * 256 + h * 32 + (c96 & 31);
                short8 bw = *(const short8*)(bWqkvt + (size_t)gcol * 256 + ks * 32 + kw * 8);
                qacc[cf] = __builtin_amdgcn_mfma_f32_16x16x32_bf16(ay[ks], bw, qacc[cf], 0, 0, 0);
            }
        }
#pragma unroll
        for (int cf = 0; cf < 3; ++cf) {
            int c96 = cq * 48 + cf * 16 + l15;
            int which = c96 >> 5, d = c96 & 31;
#pragma unroll
            for (int jj = 0; jj < 4; ++jj) {
                int r = rt * 16 + kw * 4 + jj;
                unsigned short ub = f2u(qacc[cf][jj]);
                if (which == 0) qb[r][d] = ub;
                else if (which == 1) kb[r][d] = ub;
                else Vt[d][r] = ub;
            }
        }
        __syncthreads();
        if (wave < 2) {
            short8 aq = *(const short8*)(&qb[wave * 16 + l15][kw * 8]);
            floatx4 sacc[2];
#pragma unroll
            for (int cf = 0; cf < 2; ++cf) {
                short8 bk = *(const short8*)(&kb[cf * 16 + l15][kw * 8]);
                sacc[cf] = __builtin_amdgcn_mfma_f32_16x16x32_bf16(aq, bk,
                            (floatx4){0.f, 0.f, 0.f, 0.f}, 0, 0, 0);
            }
#pragma unroll
            for (int jj = 0; jj < 4; ++jj) {
                float s0 = sacc[0][jj] * sc;
                float s1 = sacc[1][jj] * sc;
                float mx = fmaxf(s0, s1);
                mx = fmaxf(mx, __shfl_xor(mx, 1));
                mx = fmaxf(mx, __shfl_xor(mx, 2));
                mx = fmaxf(mx, __shfl_xor(mx, 4));
                mx = fmaxf(mx, __shfl_xor(mx, 8));
                float e0 = __expf(s0 - mx), e1 = __expf(s1 - mx);
                float sum = e0 + e1;
                sum += __shfl_xor(sum, 1);
                sum += __shfl_xor(sum, 2);
                sum += __shfl_xor(sum, 4);
                sum += __shfl_xor(sum, 8);
                float inv = 1.f / sum;
                int r = wave * 16 + kw * 4 + jj;
                Pb[r][l15] = f2u(e0 * inv);
                Pb[r][16 + l15] = f2u(e1 * inv);
            }
        }
        __syncthreads();
        {
            short8 ap = *(const short8*)(&Pb[rt * 16 + l15][kw * 8]);
            short8 bv = *(const short8*)(&Vt[cq * 16 + l15][kw * 8]);
            floatx4 oo = __builtin_amdgcn_mfma_f32_16x16x32_bf16(ap, bv,
                          (floatx4){0.f, 0.f, 0.f, 0.f}, 0, 0, 0);
#pragma unroll
            for (int jj = 0; jj < 4; ++jj)
                Ob[rt * 16 + kw * 4 + jj][cq * 16 + l15] = f2u(oo[jj]);
        }
        __syncthreads();
        {
            short8 ao = *(const short8*)(&Ob[rt * 16 + l15][kw * 8]);
#pragma unroll
            for (int cf = 0; cf < 8; ++cf) {
                int gcol = cq * 128 + cf * 16 + l15;
                short8 bw = *(const short8*)(bWpt + (size_t)gcol * 256 + h * 32 + kw * 8);
                pacc[cf] = __builtin_amdgcn_mfma_f32_16x16x32_bf16(ao, bw, pacc[cf], 0, 0, 0);
            }
        }
        __syncthreads();
    }
#pragma unroll
    for (int cf = 0; cf < 8; ++cf)
#pragma unroll
        for (int jj = 0; jj < 4; ++jj)
            Z2[rt * 16 + kw * 4 + jj][cq * 128 + cf * 16 + l15] = f2u(pacc[cf][jj]);
    __syncthreads();

    short8 az[8];
#pragma unroll
    for (int ks = 0; ks < 8; ++ks)
        az[ks] = *(const short8*)(&Z2[rt * 16 + l15][ks * 32 + kw * 8]);

    floatx4 oacc2[8];
#pragma unroll
    for (int cf = 0; cf < 8; ++cf) {
        float bb = B2[cq * 128 + cf * 16 + l15];
        oacc2[cf] = (floatx4){bb, bb, bb, bb};
    }
    for (int pass = 0; pass < 16; ++pass) {
        floatx4 facc[2];
#pragma unroll
        for (int cf = 0; cf < 2; ++cf) {
            int col = pass * 64 + cq * 32 + cf * 16 + l15;
            float bb = B1[col];
            facc[cf] = (floatx4){bb, bb, bb, bb};
        }
#pragma unroll
        for (int ks = 0; ks < 8; ++ks) {
#pragma unroll
            for (int cf = 0; cf < 2; ++cf) {
                int col = pass * 64 + cq * 32 + cf * 16 + l15;
                short8 bw = *(const short8*)(bW1t + (size_t)col * 256 + ks * 32 + kw * 8);
                facc[cf] = __builtin_amdgcn_mfma_f32_16x16x32_bf16(az[ks], bw, facc[cf], 0, 0, 0);
            }
        }
#pragma unroll
        for (int cf = 0; cf < 2; ++cf)
#pragma unroll
            for (int jj = 0; jj < 4; ++jj)
                Hbuf[rt * 16 + kw * 4 + jj][cq * 32 + cf * 16 + l15] = f2u(gelu_exact(facc[cf][jj]));
        __syncthreads();
#pragma unroll
        for (int ks = 0; ks < 2; ++ks) {
            short8 ah = *(const short8*)(&Hbuf[rt * 16 + l15][ks * 32 + kw * 8]);
#pragma unroll
            for (int cf = 0; cf < 8; ++cf) {
                int gcol = cq * 128 + cf * 16 + l15;
                short8 bw = *(const short8*)(bW2t + (size_t)gcol * 1024 + pass * 64 + ks * 32 + kw * 8);
                oacc2[cf] = __builtin_amdgcn_mfma_f32_16x16x32_bf16(ah, bw, oacc2[cf], 0, 0, 0);
            }
        }
        __syncthreads();
    }
#pragma unroll
    for (int cf = 0; cf < 8; ++cf)
#pragma unroll
        for (int jj = 0; jj < 4; ++jj) {
            int r = rt * 16 + kw * 4 + jj;
            int c = cq * 128 + cf * 16 + l15;
            zout[(size_t)bt * 8192 + r * 256 + c] = oacc2[cf][jj];
        }
}

// ===================== Kernel Z3: broadcast add over N ======================
__global__ __launch_bounds__(256) void zadd_k(
    const float* __restrict__ zout, float* __restrict__ out)
{
    int w = blockIdx.x, t = threadIdx.x;
    size_t base = (size_t)w * 16384;
    float zv = zout[(size_t)w * 256 + t];
    for (int nn = 0; nn < 64; ++nn)
        out[base + (size_t)nn * 256 + t] += zv;
}

extern "C" void kernel_launch(void* const* d_in, const int* in_sizes, int n_in,
                              void* d_out, int out_size, void* d_ws, size_t ws_size,
                              hipStream_t stream) {
    (void)in_sizes; (void)n_in; (void)out_size; (void)ws_size;
    const float* x        = (const float*)d_in[0];
    const float* mask     = (const float*)d_in[1];
    const float* adj      = (const float*)d_in[2];
    const float* dn1_g    = (const float*)d_in[3];
    const float* dn1_b    = (const float*)d_in[4];
    const float* dn2_g    = (const float*)d_in[5];
    const float* dn2_b    = (const float*)d_in[6];
    const float* bn1_g    = (const float*)d_in[7];
    const float* bn1_b    = (const float*)d_in[8];
    const float* d_qkv_w  = (const float*)d_in[9];
    const float* d_qkv_b  = (const float*)d_in[10];
    const float* d_proj_w = (const float*)d_in[11];
    const float* d_proj_b = (const float*)d_in[12];
    const float* d_fc1_w  = (const float*)d_in[13];
    const float* d_fc1_b  = (const float*)d_in[14];
    const float* d_fc2_w  = (const float*)d_in[15];
    const float* d_fc2_b  = (const float*)d_in[16];
    const float* b_qkv_w  = (const float*)d_in[17];
    const float* b_qkv_b  = (const float*)d_in[18];
    const float* b_proj_w = (const float*)d_in[19];
    const float* b_proj_b = (const float*)d_in[20];
    const float* b_fc1_w  = (const float*)d_in[21];
    const float* b_fc1_b  = (const float*)d_in[22];
    const float* b_fc2_w  = (const float*)d_in[23];
    const float* b_fc2_b  = (const float*)d_in[24];
    float* out = (float*)d_out;

    // workspace (shorts unless noted), ~5.1 MB total:
    // W1t 262144 | W2t 262144 | Wqkvt 196608 | Wpt 65536
    // bW1t 262144 | bW2t 262144 | bWqkvt 196608 | bWpt 65536
    // Ladj fp32 4096 | zsum fp32 262144 | zout fp32 262144
    unsigned short* W1t    = (unsigned short*)d_ws;
    unsigned short* W2t    = W1t + 262144;
    unsigned short* Wqkvt  = W2t + 262144;
    unsigned short* Wpt    = Wqkvt + 196608;
    unsigned short* bW1t   = Wpt + 65536;
    unsigned short* bW2t   = bW1t + 262144;
    unsigned short* bWqkvt = bW2t + 262144;
    unsigned short* bWpt   = bWqkvt + 196608;
    float* Ladj            = (float*)(bWpt + 65536);
    float* zsum            = Ladj + 4096;
    float* zout            = zsum + 262144;

    pack_weights_k<<<4609, 256, 0, stream>>>(d_fc1_w, d_fc2_w, d_qkv_w, d_proj_w,
                                             b_fc1_w, b_fc2_w, b_qkv_w, b_proj_w, adj,
                                             W1t, W2t, Wqkvt, Wpt,
                                             bW1t, bW2t, bWqkvt, bWpt, Ladj);
    attn_mfma_k<<<1024, 256, 0, stream>>>(x, mask, Ladj, dn1_g, dn1_b,
                                          Wqkvt, d_qkv_b, Wpt, d_proj_b, out);
    mlp_mfma_k<<<1024, 256, 0, stream>>>(mask, dn2_g, dn2_b,
                                         W1t, d_fc1_b, W2t, d_fc2_b, out, zsum);
    zcompute_k<<<32, 256, 0, stream>>>(zsum, mask, bn1_g, bn1_b,
                                       bWqkvt, b_qkv_b, bWpt, b_proj_b,
                                       bW1t, b_fc1_b, bW2t, b_fc2_b, zout);
    zadd_k<<<1024, 256, 0, stream>>>(zout, out);
}

// Round 8
// 790.836 us; speedup vs baseline: 1.3643x; 1.0459x over previous
//
#include <hip/hip_runtime.h>
#include <hip/hip_bf16.h>
#include <math.h>

typedef __attribute__((ext_vector_type(8))) short short8;
typedef __attribute__((ext_vector_type(4))) float floatx4;

__device__ __forceinline__ unsigned short f2u(float f) {
    union { float f; unsigned int i; } c; c.f = f;
    unsigned int r = c.i + 0x7FFF + ((c.i >> 16) & 1);   // round-to-nearest-even
    return (unsigned short)(r >> 16);
}
__device__ __forceinline__ float gelu_exact(float x) {
    return 0.5f * x * (1.0f + erff(x * 0.7071067811865475f));
}

// ===================== Kernel P: pack weights bf16 k-contig + Ladj table ===
__global__ __launch_bounds__(256) void pack_weights_k(
    const float* __restrict__ W1, const float* __restrict__ W2,
    const float* __restrict__ Wqkv, const float* __restrict__ Wp,
    const float* __restrict__ bW1, const float* __restrict__ bW2,
    const float* __restrict__ bWqkv, const float* __restrict__ bWp,
    const float* __restrict__ adj,
    unsigned short* __restrict__ W1t, unsigned short* __restrict__ W2t,
    unsigned short* __restrict__ Wqkvt, unsigned short* __restrict__ Wpt,
    unsigned short* __restrict__ bW1t, unsigned short* __restrict__ bW2t,
    unsigned short* __restrict__ bWqkvt, unsigned short* __restrict__ bWpt,
    float* __restrict__ Ladj)
{
    int b = blockIdx.x, t = threadIdx.x;
    if (b < 1024) {
        W1t[(size_t)b * 256 + t] = f2u(W1[(size_t)t * 1024 + b]);
    } else if (b < 1280) {
        int n = b - 1024;
        for (int it = 0; it < 4; ++it) {
            int k = it * 256 + t;
            W2t[(size_t)n * 1024 + k] = f2u(W2[(size_t)k * 256 + n]);
        }
    } else if (b < 2048) {
        int c = b - 1280;
        Wqkvt[(size_t)c * 256 + t] = f2u(Wqkv[(size_t)t * 768 + c]);
    } else if (b < 2304) {
        int c = b - 2048;
        Wpt[(size_t)c * 256 + t] = f2u(Wp[(size_t)t * 256 + c]);
    } else if (b < 3328) {
        int c = b - 2304;
        bW1t[(size_t)c * 256 + t] = f2u(bW1[(size_t)t * 1024 + c]);
    } else if (b < 3584) {
        int n = b - 3328;
        for (int it = 0; it < 4; ++it) {
            int k = it * 256 + t;
            bW2t[(size_t)n * 1024 + k] = f2u(bW2[(size_t)k * 256 + n]);
        }
    } else if (b < 4352) {
        int c = b - 3584;
        bWqkvt[(size_t)c * 256 + t] = f2u(bWqkv[(size_t)t * 768 + c]);
    } else if (b < 4608) {
        int c = b - 4352;
        bWpt[(size_t)c * 256 + t] = f2u(bWp[(size_t)t * 256 + c]);
    } else {
        for (int i = 0; i < 16; ++i) {
            int idx = t * 16 + i;
            Ladj[idx] = logf(adj[idx] + 1e-6f);
        }
    }
}

// ===================== Kernel A: fused LN1+attn+LN2+MLP per window =========
// One block per window (1024 blocks, 4 waves, (256,2)).
// LDS union (33792 B): Ybuf -> attn bufs -> Ybuf2 -> Hbuf+Wbuf.
// LN2 is computed entirely in registers from the post-attn residual (nv),
// eliminating the inter-kernel out round-trip.
__global__ __launch_bounds__(256, 2) void attn_mlp_k(
    const float* __restrict__ x, const float* __restrict__ mask,
    const float* __restrict__ Ladj,
    const float* __restrict__ g1, const float* __restrict__ be1,
    const unsigned short* __restrict__ Wqkvt, const float* __restrict__ Bqkv,
    const unsigned short* __restrict__ Wpt, const float* __restrict__ Bp,
    const float* __restrict__ g2, const float* __restrict__ be2,
    const unsigned short* __restrict__ W1t, const float* __restrict__ B1,
    const unsigned short* __restrict__ W2t, const float* __restrict__ B2,
    float* __restrict__ out, float* __restrict__ zsum)
{
    __shared__ __align__(16) unsigned char smem[33792];
    unsigned short (*Ybuf)[264] = (unsigned short (*)[264])smem;           // LN1 / LN2 staging
    unsigned short (*qb)[40]    = (unsigned short (*)[40])(smem);          //  5120
    unsigned short (*kb)[40]    = (unsigned short (*)[40])(smem + 5120);   //  5120
    unsigned short (*Vt)[72]    = (unsigned short (*)[72])(smem + 10240);  //  4608
    unsigned short (*Pb)[72]    = (unsigned short (*)[72])(smem + 14848);  //  9216
    unsigned short (*Ob)[40]    = (unsigned short (*)[40])(smem + 24064);  //  5120
    unsigned short (*Hbuf)[72]  = (unsigned short (*)[72])smem;            //  9216 (mlp)
    unsigned short* Wbuf        = (unsigned short*)(smem + 9216);          // 20480 (mlp)

    int w = blockIdx.x, p = w & 31, t = threadIdx.x;
    int wave = t >> 6, lane = t & 63;
    int l15 = lane & 15, kw = lane >> 4;
    size_t base = (size_t)w * 16384;

    // ---- LN1 -> bf16 Ybuf (no out write; x re-read later from L3) ----
    for (int it = 0; it < 16; ++it) {
        int r = it * 4 + wave;
        float vals[4]; float sum = 0.f, sq = 0.f;
#pragma unroll
        for (int k2 = 0; k2 < 4; ++k2) {
            float vv = x[base + (size_t)r * 256 + lane + 64 * k2];
            vals[k2] = vv; sum += vv; sq += vv * vv;
        }
        for (int o = 32; o > 0; o >>= 1) { sum += __shfl_xor(sum, o); sq += __shfl_xor(sq, o); }
        float mu = sum * (1.f / 256.f);
        float var = sq * (1.f / 256.f) - mu * mu;
        float rstd = rsqrtf(var + 1e-5f);
#pragma unroll
        for (int k2 = 0; k2 < 4; ++k2) {
            int c = lane + 64 * k2;
            Ybuf[r][c] = f2u((vals[k2] - mu) * rstd * g1[c] + be1[c]);
        }
    }
    __syncthreads();

    short8 ay[8];
#pragma unroll
    for (int ks = 0; ks < 8; ++ks)
        ay[ks] = *(const short8*)(&Ybuf[wave * 16 + l15][ks * 32 + kw * 8]);

    floatx4 oacc[16];
#pragma unroll
    for (int cf = 0; cf < 16; ++cf) {
        float bb = Bp[cf * 16 + l15];
        oacc[cf] = (floatx4){bb, bb, bb, bb};
    }
    __syncthreads();   // Ybuf reads complete before qb/kb/Vt overlap-writes

    const float sc = 0.17677669529663689f;

    for (int h = 0; h < 8; ++h) {
        // ---- QKV GEMM (B-frags direct from L2-resident packed weights) ----
        floatx4 qacc[6];
#pragma unroll
        for (int cf = 0; cf < 6; ++cf) {
            int gcol = (cf >> 1) * 256 + h * 32 + (cf & 1) * 16 + l15;
            float bb = Bqkv[gcol];
            qacc[cf] = (floatx4){bb, bb, bb, bb};
        }
#pragma unroll
        for (int ks = 0; ks < 8; ++ks) {
            short8 bw[6];
#pragma unroll
            for (int cf = 0; cf < 6; ++cf) {
                int gcol = (cf >> 1) * 256 + h * 32 + (cf & 1) * 16 + l15;
                bw[cf] = *(const short8*)(Wqkvt + (size_t)gcol * 256 + ks * 32 + kw * 8);
            }
#pragma unroll
            for (int cf = 0; cf < 6; ++cf)
                qacc[cf] = __builtin_amdgcn_mfma_f32_16x16x32_bf16(ay[ks], bw[cf], qacc[cf], 0, 0, 0);
        }
#pragma unroll
        for (int cf = 0; cf < 6; ++cf)
#pragma unroll
            for (int jj = 0; jj < 4; ++jj) {
                int r = wave * 16 + kw * 4 + jj;
                int d = (cf & 1) * 16 + l15;
                unsigned short ub = f2u(qacc[cf][jj]);
                if (cf < 2) qb[r][d] = ub;
                else if (cf < 4) kb[r][d] = ub;
                else Vt[d][r] = ub;
            }
        __syncthreads();   // kb/Vt ready for cross-wave reads

        // ---- scores S = Q K^T + in-register softmax (Ladj from L2) ----
        short8 aq = *(const short8*)(&qb[wave * 16 + l15][kw * 8]);
        floatx4 sacc[4];
#pragma unroll
        for (int cf = 0; cf < 4; ++cf) {
            short8 bk = *(const short8*)(&kb[cf * 16 + l15][kw * 8]);
            sacc[cf] = __builtin_amdgcn_mfma_f32_16x16x32_bf16(aq, bk,
                        (floatx4){0.f, 0.f, 0.f, 0.f}, 0, 0, 0);
        }
#pragma unroll
        for (int jj = 0; jj < 4; ++jj) {
            int r = wave * 16 + kw * 4 + jj;
            float s0 = sacc[0][jj] * sc + Ladj[r * 64 + 0 * 16 + l15];
            float s1 = sacc[1][jj] * sc + Ladj[r * 64 + 1 * 16 + l15];
            float s2 = sacc[2][jj] * sc + Ladj[r * 64 + 2 * 16 + l15];
            float s3 = sacc[3][jj] * sc + Ladj[r * 64 + 3 * 16 + l15];
            float mx = fmaxf(fmaxf(s0, s1), fmaxf(s2, s3));
            mx = fmaxf(mx, __shfl_xor(mx, 1));
            mx = fmaxf(mx, __shfl_xor(mx, 2));
            mx = fmaxf(mx, __shfl_xor(mx, 4));
            mx = fmaxf(mx, __shfl_xor(mx, 8));
            float e0 = __expf(s0 - mx), e1 = __expf(s1 - mx);
            float e2 = __expf(s2 - mx), e3 = __expf(s3 - mx);
            float sum = e0 + e1 + e2 + e3;
            sum += __shfl_xor(sum, 1);
            sum += __shfl_xor(sum, 2);
            sum += __shfl_xor(sum, 4);
            sum += __shfl_xor(sum, 8);
            float inv = 1.f / sum;
            Pb[r][0 * 16 + l15] = f2u(e0 * inv);
            Pb[r][1 * 16 + l15] = f2u(e1 * inv);
            Pb[r][2 * 16 + l15] = f2u(e2 * inv);
            Pb[r][3 * 16 + l15] = f2u(e3 * inv);
        }
        // Pb is same-wave write->read: no barrier needed.

        // ---- PV: O = P @ V ----
        floatx4 oacc2[2];
#pragma unroll
        for (int cf2 = 0; cf2 < 2; ++cf2) oacc2[cf2] = (floatx4){0.f, 0.f, 0.f, 0.f};
#pragma unroll
        for (int ks = 0; ks < 2; ++ks) {
            short8 ap = *(const short8*)(&Pb[wave * 16 + l15][ks * 32 + kw * 8]);
#pragma unroll
            for (int cf2 = 0; cf2 < 2; ++cf2) {
                short8 bv = *(const short8*)(&Vt[cf2 * 16 + l15][ks * 32 + kw * 8]);
                oacc2[cf2] = __builtin_amdgcn_mfma_f32_16x16x32_bf16(ap, bv, oacc2[cf2], 0, 0, 0);
            }
        }
#pragma unroll
        for (int cf2 = 0; cf2 < 2; ++cf2)
#pragma unroll
            for (int jj = 0; jj < 4; ++jj)
                Ob[wave * 16 + kw * 4 + jj][cf2 * 16 + l15] = f2u(oacc2[cf2][jj]);
        __syncthreads();   // all cross-wave kb/Vt reads done before next head's writes

        // ---- proj accumulate (Ob same-wave; Wpt from L2) ----
        short8 ao = *(const short8*)(&Ob[wave * 16 + l15][kw * 8]);
#pragma unroll
        for (int cf = 0; cf < 16; ++cf) {
            short8 bw = *(const short8*)(Wpt + (size_t)(cf * 16 + l15) * 256 + h * 32 + kw * 8);
            oacc[cf] = __builtin_amdgcn_mfma_f32_16x16x32_bf16(ao, bw, oacc[cf], 0, 0, 0);
        }
    }

    // ---- residual in regs: nv = x + attn*mask (x re-read, L3-hot; batched) ----
#pragma unroll
    for (int jj = 0; jj < 4; ++jj) {
        int r = wave * 16 + kw * 4 + jj;
        float mv = mask[p * 64 + r];
        float xv[16];
#pragma unroll
        for (int cf = 0; cf < 16; ++cf)
            xv[cf] = x[base + (size_t)r * 256 + cf * 16 + l15];
#pragma unroll
        for (int cf = 0; cf < 16; ++cf)
            oacc[cf][jj] = xv[cf] + oacc[cf][jj] * mv;      // nv (x5 after attn)
    }

    // ---- LN2 fully in registers; write nv to out; y2 -> oacc in place ----
    float g2r[16], be2r[16];
#pragma unroll
    for (int cf = 0; cf < 16; ++cf) {
        g2r[cf]  = g2[cf * 16 + l15];
        be2r[cf] = be2[cf * 16 + l15];
    }
#pragma unroll
    for (int jj = 0; jj < 4; ++jj) {
        int r = wave * 16 + kw * 4 + jj;
        float s1 = 0.f, s2 = 0.f;
#pragma unroll
        for (int cf = 0; cf < 16; ++cf) {
            float v = oacc[cf][jj];
            s1 += v; s2 += v * v;
        }
        s1 += __shfl_xor(s1, 1); s2 += __shfl_xor(s2, 1);
        s1 += __shfl_xor(s1, 2); s2 += __shfl_xor(s2, 2);
        s1 += __shfl_xor(s1, 4); s2 += __shfl_xor(s2, 4);
        s1 += __shfl_xor(s1, 8); s2 += __shfl_xor(s2, 8);
        float mu = s1 * (1.f / 256.f);
        float var = s2 * (1.f / 256.f) - mu * mu;
        float rstd = rsqrtf(var + 1e-5f);
#pragma unroll
        for (int cf = 0; cf < 16; ++cf)
            out[base + (size_t)r * 256 + cf * 16 + l15] = oacc[cf][jj];   // nv
#pragma unroll
        for (int cf = 0; cf < 16; ++cf)
            oacc[cf][jj] = (oacc[cf][jj] - mu) * rstd * g2r[cf] + be2r[cf];  // y2
    }
    __syncthreads();   // all waves done with attn LDS before Ybuf2 overwrite

#pragma unroll
    for (int jj = 0; jj < 4; ++jj) {
        int r = wave * 16 + kw * 4 + jj;
#pragma unroll
        for (int cf = 0; cf < 16; ++cf)
            Ybuf[r][cf * 16 + l15] = f2u(oacc[cf][jj]);
    }
    // ay2 hoist: same-wave write->read, no barrier
    short8 ay2[8];
#pragma unroll
    for (int ks = 0; ks < 8; ++ks)
        ay2[ks] = *(const short8*)(&Ybuf[wave * 16 + l15][ks * 32 + kw * 8]);
    __syncthreads();   // Ybuf2 dead; Hbuf/Wbuf may now overwrite

    // ---- MLP (Wbuf-staged, R3-proven loop) ----
    floatx4 macc[4][4];
#pragma unroll
    for (int m = 0; m < 4; ++m)
#pragma unroll
        for (int j = 0; j < 4; ++j) {
            float bb = B2[wave * 64 + j * 16 + l15];
            macc[m][j] = (floatx4){bb, bb, bb, bb};
        }

    for (int pass = 0; pass < 16; ++pass) {
        floatx4 facc[4];
#pragma unroll
        for (int j = 0; j < 4; ++j) {
            float bb = B1[pass * 64 + j * 16 + l15];
            facc[j] = (floatx4){bb, bb, bb, bb};
        }
        {
            int nr = t >> 2, c = t & 3;
            *(short8*)(Wbuf + nr * 40 + c * 8) =
                *(const short8*)(W1t + (size_t)(pass * 64 + nr) * 256 + c * 8);
        }
        __syncthreads();
        for (int ks = 0; ks < 8; ++ks) {
            if (ks + 1 < 8) {
                int nr = t >> 2, c = t & 3;
                *(short8*)(Wbuf + ((ks + 1) & 1) * 2560 + nr * 40 + c * 8) =
                    *(const short8*)(W1t + (size_t)(pass * 64 + nr) * 256 + (ks + 1) * 32 + c * 8);
            }
            int hh = (ks & 1) * 2560;
            short8 bf[4];
#pragma unroll
            for (int j = 0; j < 4; ++j)
                bf[j] = *(const short8*)(Wbuf + hh + (j * 16 + l15) * 40 + kw * 8);
#pragma unroll
            for (int j = 0; j < 4; ++j)
                facc[j] = __builtin_amdgcn_mfma_f32_16x16x32_bf16(ay2[ks], bf[j], facc[j], 0, 0, 0);
            __syncthreads();
        }
#pragma unroll
        for (int j = 0; j < 4; ++j)
#pragma unroll
            for (int jj = 0; jj < 4; ++jj)
                Hbuf[wave * 16 + kw * 4 + jj][j * 16 + l15] = f2u(gelu_exact(facc[j][jj]));
        __syncthreads();

        for (int ks2 = 0; ks2 < 2; ++ks2) {
            for (int it = 0; it < 4; ++it) {
                int idx = it * 256 + t;
                int nr = idx >> 2, c = idx & 3;
                *(short8*)(Wbuf + nr * 40 + c * 8) =
                    *(const short8*)(W2t + (size_t)nr * 1024 + pass * 64 + ks2 * 32 + c * 8);
            }
            __syncthreads();
            short8 af[4], bf[4];
#pragma unroll
            for (int m = 0; m < 4; ++m)
                af[m] = *(const short8*)(&Hbuf[m * 16 + l15][ks2 * 32 + kw * 8]);
#pragma unroll
            for (int j = 0; j < 4; ++j)
                bf[j] = *(const short8*)(Wbuf + (wave * 64 + j * 16 + l15) * 40 + kw * 8);
#pragma unroll
            for (int m = 0; m < 4; ++m)
#pragma unroll
                for (int j = 0; j < 4; ++j)
                    macc[m][j] = __builtin_amdgcn_mfma_f32_16x16x32_bf16(af[m], bf[j], macc[m][j], 0, 0, 0);
            __syncthreads();
        }
    }

    // ---- final epilogue: out = nv + mlp*mask (batched RMW, L2-hot); zsum ----
    float zp[4] = {0.f, 0.f, 0.f, 0.f};
#pragma unroll
    for (int m = 0; m < 4; ++m) {
        float ov[4][4];
#pragma unroll
        for (int jj = 0; jj < 4; ++jj) {
            int r = m * 16 + kw * 4 + jj;
#pragma unroll
            for (int j = 0; j < 4; ++j)
                ov[jj][j] = out[base + (size_t)r * 256 + wave * 64 + j * 16 + l15];
        }
#pragma unroll
        for (int jj = 0; jj < 4; ++jj) {
            int r = m * 16 + kw * 4 + jj;
            float mv = mask[p * 64 + r];
#pragma unroll
            for (int j = 0; j < 4; ++j) {
                float nv2 = ov[jj][j] + macc[m][j][jj] * mv;
                out[base + (size_t)r * 256 + wave * 64 + j * 16 + l15] = nv2;
                zp[j] += mv * nv2;
            }
        }
    }
#pragma unroll
    for (int j = 0; j < 4; ++j) {
        zp[j] += __shfl_xor(zp[j], 16);
        zp[j] += __shfl_xor(zp[j], 32);
    }
    if (kw == 0) {
#pragma unroll
        for (int j = 0; j < 4; ++j)
            zsum[(size_t)w * 256 + wave * 64 + j * 16 + l15] = zp[j];
    }
}

// ===================== Kernel Z2: pool-finish + LN + z attn + MLP ===========
__global__ __launch_bounds__(256) void zcompute_k(
    const float* __restrict__ zsum, const float* __restrict__ mask,
    const float* __restrict__ gvec, const float* __restrict__ bvec,
    const unsigned short* __restrict__ bWqkvt, const float* __restrict__ Bqkv,
    const unsigned short* __restrict__ bWpt, const float* __restrict__ Bp,
    const unsigned short* __restrict__ bW1t, const float* __restrict__ B1,
    const unsigned short* __restrict__ bW2t, const float* __restrict__ B2,
    float* __restrict__ zout)
{
    __shared__ unsigned short Zbuf[32][264];
    __shared__ unsigned short Z2[32][264];
    __shared__ unsigned short qb[32][40], kb[32][40], Vt[32][40], Pb[32][40], Ob[32][40];
    __shared__ unsigned short Hbuf[32][72];
    __shared__ float msh[32];
    int bt = blockIdx.x, t = threadIdx.x;
    int wave = t >> 6, lane = t & 63;
    int l15 = lane & 15, kw = lane >> 4;
    int rt = wave & 1, cq = wave >> 1;

    if (t < 32) {
        float s = 0.f;
        for (int nn = 0; nn < 64; ++nn) s += mask[t * 64 + nn];
        msh[t] = fmaxf(s, 1.f);
    }
    __syncthreads();

    for (int it = 0; it < 8; ++it) {
        int r = it * 4 + wave;
        float inv_m = 1.f / msh[r];
        float vals[4]; float sum = 0.f, sq = 0.f;
#pragma unroll
        for (int k2 = 0; k2 < 4; ++k2) {
            float vv = zsum[(size_t)bt * 8192 + (size_t)r * 256 + lane + 64 * k2] * inv_m;
            vals[k2] = vv; sum += vv; sq += vv * vv;
        }
        for (int o = 32; o > 0; o >>= 1) { sum += __shfl_xor(sum, o); sq += __shfl_xor(sq, o); }
        float mu = sum * (1.f / 256.f);
        float var = sq * (1.f / 256.f) - mu * mu;
        float rstd = rsqrtf(var + 1e-5f);
#pragma unroll
        for (int k2 = 0; k2 < 4; ++k2) {
            int c = lane + 64 * k2;
            Zbuf[r][c] = f2u((vals[k2] - mu) * rstd * gvec[c] + bvec[c]);
        }
    }
    __syncthreads();

    short8 ay[8];
#pragma unroll
    for (int ks = 0; ks < 8; ++ks)
        ay[ks] = *(const short8*)(&Zbuf[rt * 16 + l15][ks * 32 + kw * 8]);

    floatx4 pacc[8];
#pragma unroll
    for (int cf = 0; cf < 8; ++cf) {
        float bb = Bp[cq * 128 + cf * 16 + l15];
        pacc[cf] = (floatx4){bb, bb, bb, bb};
    }
    const float sc = 0.17677669529663689f;

    for (int h = 0; h < 8; ++h) {
        floatx4 qacc[3];
#pragma unroll
        for (int cf = 0; cf < 3; ++cf) {
            int c96 = cq * 48 + cf * 16 + l15;
            int gcol = (c96 >> 5) * 256 + h * 32 + (c96 & 31);
            float bb = Bqkv[gcol];
            qacc[cf] = (floatx4){bb, bb, bb, bb};
        }
#pragma unroll
        for (int ks = 0; ks < 8; ++ks) {
#pragma unroll
            for (int cf = 0; cf < 3; ++cf) {
                int c96 = cq * 48 + cf * 16 + l15;
                int gcol = (c96 >> 5) * 256 + h * 32 + (c96 & 31);
                short8 bw = *(const short8*)(bWqkvt + (size_t)gcol * 256 + ks * 32 + kw * 8);
                qacc[cf] = __builtin_amdgcn_mfma_f32_16x16x32_bf16(ay[ks], bw, qacc[cf], 0, 0, 0);
            }
        }
#pragma unroll
        for (int cf = 0; cf < 3; ++cf) {
            int c96 = cq * 48 + cf * 16 + l15;
            int which = c96 >> 5, d = c96 & 31;
#pragma unroll
            for (int jj = 0; jj < 4; ++jj) {
                int r = rt * 16 + kw * 4 + jj;
                unsigned short ub = f2u(qacc[cf][jj]);
                if (which == 0) qb[r][d] = ub;
                else if (which == 1) kb[r][d] = ub;
                else Vt[d][r] = ub;
            }
        }
        __syncthreads();
        if (wave < 2) {
            short8 aq = *(const short8*)(&qb[wave * 16 + l15][kw * 8]);
            floatx4 sacc[2];
#pragma unroll
            for (int cf = 0; cf < 2; ++cf) {
                short8 bk = *(const short8*)(&kb[cf * 16 + l15][kw * 8]);
                sacc[cf] = __builtin_amdgcn_mfma_f32_16x16x32_bf16(aq, bk,
                            (floatx4){0.f, 0.f, 0.f, 0.f}, 0, 0, 0);
            }
#pragma unroll
            for (int jj = 0; jj < 4; ++jj) {
                float s0 = sacc[0][jj] * sc;
                float s1 = sacc[1][jj] * sc;
                float mx = fmaxf(s0, s1);
                mx = fmaxf(mx, __shfl_xor(mx, 1));
                mx = fmaxf(mx, __shfl_xor(mx, 2));
                mx = fmaxf(mx, __shfl_xor(mx, 4));
                mx = fmaxf(mx, __shfl_xor(mx, 8));
                float e0 = __expf(s0 - mx), e1 = __expf(s1 - mx);
                float sum = e0 + e1;
                sum += __shfl_xor(sum, 1);
                sum += __shfl_xor(sum, 2);
                sum += __shfl_xor(sum, 4);
                sum += __shfl_xor(sum, 8);
                float inv = 1.f / sum;
                int r = wave * 16 + kw * 4 + jj;
                Pb[r][l15] = f2u(e0 * inv);
                Pb[r][16 + l15] = f2u(e1 * inv);
            }
        }
        __syncthreads();
        {
            short8 ap = *(const short8*)(&Pb[rt * 16 + l15][kw * 8]);
            short8 bv = *(const short8*)(&Vt[cq * 16 + l15][kw * 8]);
            floatx4 oo = __builtin_amdgcn_mfma_f32_16x16x32_bf16(ap, bv,
                          (floatx4){0.f, 0.f, 0.f, 0.f}, 0, 0, 0);
#pragma unroll
            for (int jj = 0; jj < 4; ++jj)
                Ob[rt * 16 + kw * 4 + jj][cq * 16 + l15] = f2u(oo[jj]);
        }
        __syncthreads();
        {
            short8 ao = *(const short8*)(&Ob[rt * 16 + l15][kw * 8]);
#pragma unroll
            for (int cf = 0; cf < 8; ++cf) {
                int gcol = cq * 128 + cf * 16 + l15;
                short8 bw = *(const short8*)(bWpt + (size_t)gcol * 256 + h * 32 + kw * 8);
                pacc[cf] = __builtin_amdgcn_mfma_f32_16x16x32_bf16(ao, bw, pacc[cf], 0, 0, 0);
            }
        }
        __syncthreads();
    }
#pragma unroll
    for (int cf = 0; cf < 8; ++cf)
#pragma unroll
        for (int jj = 0; jj < 4; ++jj)
            Z2[rt * 16 + kw * 4 + jj][cq * 128 + cf * 16 + l15] = f2u(pacc[cf][jj]);
    __syncthreads();

    short8 az[8];
#pragma unroll
    for (int ks = 0; ks < 8; ++ks)
        az[ks] = *(const short8*)(&Z2[rt * 16 + l15][ks * 32 + kw * 8]);

    floatx4 oacc2[8];
#pragma unroll
    for (int cf = 0; cf < 8; ++cf) {
        float bb = B2[cq * 128 + cf * 16 + l15];
        oacc2[cf] = (floatx4){bb, bb, bb, bb};
    }
    for (int pass = 0; pass < 16; ++pass) {
        floatx4 facc[2];
#pragma unroll
        for (int cf = 0; cf < 2; ++cf) {
            int col = pass * 64 + cq * 32 + cf * 16 + l15;
            float bb = B1[col];
            facc[cf] = (floatx4){bb, bb, bb, bb};
        }
#pragma unroll
        for (int ks = 0; ks < 8; ++ks) {
#pragma unroll
            for (int cf = 0; cf < 2; ++cf) {
                int col = pass * 64 + cq * 32 + cf * 16 + l15;
                short8 bw = *(const short8*)(bW1t + (size_t)col * 256 + ks * 32 + kw * 8);
                facc[cf] = __builtin_amdgcn_mfma_f32_16x16x32_bf16(az[ks], bw, facc[cf], 0, 0, 0);
            }
        }
#pragma unroll
        for (int cf = 0; cf < 2; ++cf)
#pragma unroll
            for (int jj = 0; jj < 4; ++jj)
                Hbuf[rt * 16 + kw * 4 + jj][cq * 32 + cf * 16 + l15] = f2u(gelu_exact(facc[cf][jj]));
        __syncthreads();
#pragma unroll
        for (int ks = 0; ks < 2; ++ks) {
            short8 ah = *(const short8*)(&Hbuf[rt * 16 + l15][ks * 32 + kw * 8]);
#pragma unroll
            for (int cf = 0; cf < 8; ++cf) {
                int gcol = cq * 128 + cf * 16 + l15;
                short8 bw = *(const short8*)(bW2t + (size_t)gcol * 1024 + pass * 64 + ks * 32 + kw * 8);
                oacc2[cf] = __builtin_amdgcn_mfma_f32_16x16x32_bf16(ah, bw, oacc2[cf], 0, 0, 0);
            }
        }
        __syncthreads();
    }
#pragma unroll
    for (int cf = 0; cf < 8; ++cf)
#pragma unroll
        for (int jj = 0; jj < 4; ++jj) {
            int r = rt * 16 + kw * 4 + jj;
            int c = cq * 128 + cf * 16 + l15;
            zout[(size_t)bt * 8192 + r * 256 + c] = oacc2[cf][jj];
        }
}

// ===================== Kernel Z3: broadcast add over N ======================
__global__ __launch_bounds__(256) void zadd_k(
    const float* __restrict__ zout, float* __restrict__ out)
{
    int w = blockIdx.x, t = threadIdx.x;
    size_t base = (size_t)w * 16384;
    float zv = zout[(size_t)w * 256 + t];
    for (int nn = 0; nn < 64; ++nn)
        out[base + (size_t)nn * 256 + t] += zv;
}

extern "C" void kernel_launch(void* const* d_in, const int* in_sizes, int n_in,
                              void* d_out, int out_size, void* d_ws, size_t ws_size,
                              hipStream_t stream) {
    (void)in_sizes; (void)n_in; (void)out_size; (void)ws_size;
    const float* x        = (const float*)d_in[0];
    const float* mask     = (const float*)d_in[1];
    const float* adj      = (const float*)d_in[2];
    const float* dn1_g    = (const float*)d_in[3];
    const float* dn1_b    = (const float*)d_in[4];
    const float* dn2_g    = (const float*)d_in[5];
    const float* dn2_b    = (const float*)d_in[6];
    const float* bn1_g    = (const float*)d_in[7];
    const float* bn1_b    = (const float*)d_in[8];
    const float* d_qkv_w  = (const float*)d_in[9];
    const float* d_qkv_b  = (const float*)d_in[10];
    const float* d_proj_w = (const float*)d_in[11];
    const float* d_proj_b = (const float*)d_in[12];
    const float* d_fc1_w  = (const float*)d_in[13];
    const float* d_fc1_b  = (const float*)d_in[14];
    const float* d_fc2_w  = (const float*)d_in[15];
    const float* d_fc2_b  = (const float*)d_in[16];
    const float* b_qkv_w  = (const float*)d_in[17];
    const float* b_qkv_b  = (const float*)d_in[18];
    const float* b_proj_w = (const float*)d_in[19];
    const float* b_proj_b = (const float*)d_in[20];
    const float* b_fc1_w  = (const float*)d_in[21];
    const float* b_fc1_b  = (const float*)d_in[22];
    const float* b_fc2_w  = (const float*)d_in[23];
    const float* b_fc2_b  = (const float*)d_in[24];
    float* out = (float*)d_out;

    // workspace (shorts unless noted), ~5.1 MB total
    unsigned short* W1t    = (unsigned short*)d_ws;
    unsigned short* W2t    = W1t + 262144;
    unsigned short* Wqkvt  = W2t + 262144;
    unsigned short* Wpt    = Wqkvt + 196608;
    unsigned short* bW1t   = Wpt + 65536;
    unsigned short* bW2t   = bW1t + 262144;
    unsigned short* bWqkvt = bW2t + 262144;
    unsigned short* bWpt   = bWqkvt + 196608;
    float* Ladj            = (float*)(bWpt + 65536);
    float* zsum            = Ladj + 4096;
    float* zout            = zsum + 262144;

    pack_weights_k<<<4609, 256, 0, stream>>>(d_fc1_w, d_fc2_w, d_qkv_w, d_proj_w,
                                             b_fc1_w, b_fc2_w, b_qkv_w, b_proj_w, adj,
                                             W1t, W2t, Wqkvt, Wpt,
                                             bW1t, bW2t, bWqkvt, bWpt, Ladj);
    attn_mlp_k<<<1024, 256, 0, stream>>>(x, mask, Ladj, dn1_g, dn1_b,
                                         Wqkvt, d_qkv_b, Wpt, d_proj_b,
                                         dn2_g, dn2_b,
                                         W1t, d_fc1_b, W2t, d_fc2_b,
                                         out, zsum);
    zcompute_k<<<32, 256, 0, stream>>>(zsum, mask, bn1_g, bn1_b,
                                       bWqkvt, b_qkv_b, bWpt, b_proj_b,
                                       bW1t, b_fc1_b, bW2t, b_fc2_b, zout);
    zadd_k<<<1024, 256, 0, stream>>>(zout, out);
}